// Round 1
// baseline (2477.063 us; speedup 1.0000x reference)
//
#include <hip/hip_runtime.h>
#include <cstdint>
#include <algorithm>

// ---------------- problem constants ----------------
#define N1c 100000
#define N2c 80000
#define EPSc 1e-5f
#define STRIDE_N1 102400   // 100 blocks of 1024 (>= N1+1 bins)
#define STRIDE_N2 81920    // 80 blocks of 1024  (>= N2+1 bins)

// ---------------- CSR build: one pass for ALL k-chunks of a layer ----------
__global__ __launch_bounds__(256) void rank2d_kernel(
    const int* __restrict__ out_idx, int* __restrict__ rank,
    int* __restrict__ bins, int E, int M, int q, int stride)
{
    for (int e = blockIdx.x * 256 + threadIdx.x; e < E; e += gridDim.x * 256) {
        int chunk = (e / M) / q;
        rank[e] = atomicAdd(&bins[chunk * stride + out_idx[e]], 1);
    }
}

__global__ __launch_bounds__(256) void scan1(
    const int* __restrict__ bins, int* __restrict__ ptr,
    int* __restrict__ bsums, int n)
{
    __shared__ int lds[256];
    int base = blockIdx.x * 1024;
    int v[4]; int t = 0;
    #pragma unroll
    for (int i = 0; i < 4; ++i) {
        int idx = base + threadIdx.x * 4 + i;
        v[i] = idx < n ? bins[idx] : 0;
        t += v[i];
    }
    lds[threadIdx.x] = t; __syncthreads();
    for (int off = 1; off < 256; off <<= 1) {
        int x = threadIdx.x >= off ? lds[threadIdx.x - off] : 0;
        __syncthreads();
        lds[threadIdx.x] += x;
        __syncthreads();
    }
    int run = lds[threadIdx.x] - t;
    if (threadIdx.x == 255) bsums[blockIdx.x] = lds[255];
    #pragma unroll
    for (int i = 0; i < 4; ++i) {
        int idx = base + threadIdx.x * 4 + i;
        if (idx < n) ptr[idx] = run;
        run += v[i];
    }
}

// serial exclusive scan of block sums, carry reset at chunk boundaries
__global__ __launch_bounds__(64) void scan2s(
    int* __restrict__ bsums, int bpc, int nch)
{
    int c = threadIdx.x;
    if (c < nch) {
        int run = 0;
        for (int i = 0; i < bpc; ++i) {
            int idx = c * bpc + i;
            int t = bsums[idx]; bsums[idx] = run; run += t;
        }
    }
}

__global__ __launch_bounds__(256) void scan3(
    int* __restrict__ ptr, const int* __restrict__ bsums, int n)
{
    int idx = blockIdx.x * 1024 + threadIdx.x * 4;
    int add = bsums[blockIdx.x];
    #pragma unroll
    for (int i = 0; i < 4; ++i)
        if (idx + i < n) ptr[idx + i] += add;
}

// ---------------- conv1a special: scatter (x_val, k) 8B per edge ----------
__global__ __launch_bounds__(256) void scatter_1a(
    const float* __restrict__ x, const int* __restrict__ iin,
    const int* __restrict__ iout, const int* __restrict__ ptr,
    const int* __restrict__ rank, float2* __restrict__ payload, int E, int M)
{
    for (int e = blockIdx.x * 256 + threadIdx.x; e < E; e += gridDim.x * 256) {
        int k = e / M;
        float2 p; p.x = x[iin[e]]; p.y = __int_as_float(k);
        payload[ptr[iout[e]] + rank[e]] = p;
    }
}

// out[o][c] = relu( sum_e val_e * W[k_e][c] ), W (125x32) in LDS
__global__ __launch_bounds__(256) void phaseB_1a(
    const float2* __restrict__ payload, const int* __restrict__ ptr,
    const float* __restrict__ W, float* __restrict__ out, int n)
{
    __shared__ float Wl[125 * 32];
    for (int i = threadIdx.x; i < 125 * 32; i += 256) Wl[i] = W[i];
    __syncthreads();
    int total = n * 32;
    for (int idx = blockIdx.x * 256 + threadIdx.x; idx < total; idx += gridDim.x * 256) {
        int o = idx >> 5, c = idx & 31;
        int s0 = ptr[o], s1 = ptr[o + 1];
        float acc = 0.f;
        for (int s = s0; s < s1; ++s) {
            float2 p = payload[s];
            acc = fmaf(p.x, Wl[(__float_as_int(p.y) << 5) + c], acc);
        }
        out[idx] = fmaxf(acc, 0.f);
    }
}

// ---------------- Phase A: tiled gather-GEMM, 8xTC register tiles ---------
// Thread tile = TP pairs x TC couts. W row stride WST (>=CTILE for cout-split).
// GMODE: 0 = plain gather, 2 = BN(scale/shift)+ReLU at gather.
// CINC is a tuning knob: smaller CINC => smaller LDS footprint => more
// blocks/CU (occupancy). 67KB @CINC=64 capped conv3 layers at 2 blocks/CU
// (20.6% occ, VALUBusy 56%); CINC=32 -> 33.8KB -> 4 blocks/CU.
template <int CIN, int CINC, int CTILE, int WST, int TP, int TC, int GMODE>
__global__ __launch_bounds__(256) void phaseA8(
    const float* __restrict__ feats, const float* __restrict__ W,
    const int* __restrict__ in_idx, const int* __restrict__ out_idx,
    const int* __restrict__ ptr, const int* __restrict__ rank,
    float* __restrict__ contrib, int M,
    const float* __restrict__ sc, const float* __restrict__ sh)
{
    constexpr int NCG = CTILE / TC;      // cout groups
    constexpr int PPG = 256 / NCG;       // pair groups
    constexpr int PP  = PPG * TP;        // pairs per block
    constexpr int NCH  = CIN / CINC;
    constexpr int LOADERS = 256 / PP;
    constexpr int SITER = CINC / 4 / LOADERS;
    constexpr int FTS = PP + 4;          // multiple of 4
    static_assert(SITER >= 1, "CINC too small for loader layout");

    const int k = blockIdx.y;
    __shared__ float Wl[CINC][CTILE];
    __shared__ float ft[CINC][FTS];
    __shared__ int sslot[PP];

    const int cg = threadIdx.x % NCG;
    const int pg = threadIdx.x / NCG;
    const int p0 = pg * TP;
    const int pl = threadIdx.x % PP;
    const int ll = threadIdx.x / PP;

    const int* iin  = in_idx  + (size_t)k * M;
    const int* iout = out_idx + (size_t)k * M;
    const int* rk   = rank    + (size_t)k * M;
    const float* Wk = W + (size_t)k * CIN * WST;

    for (int base = blockIdx.x * PP; base < M; base += gridDim.x * PP) {
        float acc[TP][TC];
        #pragma unroll
        for (int p = 0; p < TP; ++p)
            #pragma unroll
            for (int c = 0; c < TC; ++c) acc[p][c] = 0.f;

        #pragma unroll
        for (int ch = 0; ch < NCH; ++ch) {
            __syncthreads();
            // stage W chunk (restaged per chunk; once when NCH==1)
            for (int i = threadIdx.x; i < CINC * (CTILE / 4); i += 256) {
                int j = i / (CTILE / 4), c4 = (i % (CTILE / 4)) * 4;
                *(float4*)&Wl[j][c4] =
                    *(const float4*)(Wk + (size_t)(ch * CINC + j) * WST + c4);
            }
            int p = base + pl;
            if (p < M) {
                if (ch == 0 && threadIdx.x < PP)
                    sslot[pl] = ptr[iout[p]] + rk[p];
                const float* fr = feats + (size_t)iin[p] * CIN + ch * CINC;
                #pragma unroll
                for (int i = 0; i < SITER; ++i) {
                    int j4 = (ll + i * LOADERS) * 4;
                    float4 v = *(const float4*)(fr + j4);
                    if (GMODE == 2) {
                        float4 s4 = *(const float4*)(sc + ch * CINC + j4);
                        float4 h4 = *(const float4*)(sh + ch * CINC + j4);
                        v.x = fmaxf(fmaf(v.x, s4.x, h4.x), 0.f);
                        v.y = fmaxf(fmaf(v.y, s4.y, h4.y), 0.f);
                        v.z = fmaxf(fmaf(v.z, s4.z, h4.z), 0.f);
                        v.w = fmaxf(fmaf(v.w, s4.w, h4.w), 0.f);
                    }
                    ft[j4 + 0][pl] = v.x;
                    ft[j4 + 1][pl] = v.y;
                    ft[j4 + 2][pl] = v.z;
                    ft[j4 + 3][pl] = v.w;
                }
            }
            __syncthreads();

            #pragma unroll 4
            for (int j = 0; j < CINC; ++j) {
                float fv[TP], wv[TC];
                #pragma unroll
                for (int g = 0; g < TP / 4; ++g)
                    *(float4*)&fv[g * 4] = *(const float4*)&ft[j][p0 + g * 4];
                #pragma unroll
                for (int g = 0; g < TC / 4; ++g)
                    *(float4*)&wv[g * 4] = *(const float4*)&Wl[j][cg * TC + g * 4];
                #pragma unroll
                for (int p = 0; p < TP; ++p)
                    #pragma unroll
                    for (int c = 0; c < TC; ++c)
                        acc[p][c] = fmaf(fv[p], wv[c], acc[p][c]);
            }
        }

        #pragma unroll
        for (int q = 0; q < TP; ++q) {
            if (base + p0 + q < M) {
                size_t s = (size_t)sslot[p0 + q];
                #pragma unroll
                for (int g = 0; g < TC / 4; ++g) {
                    float4 o4;
                    o4.x = acc[q][g * 4 + 0]; o4.y = acc[q][g * 4 + 1];
                    o4.z = acc[q][g * 4 + 2]; o4.w = acc[q][g * 4 + 3];
                    *(float4*)&contrib[s * CTILE + cg * TC + g * 4] = o4;
                }
            }
        }
    }
}

// ---------------- Phase B: segmented sum (+optional fused fp64 BN stats) ---
template <int CSTR, bool STATS>
__global__ __launch_bounds__(256) void phaseB8(
    const float* __restrict__ contrib, const int* __restrict__ ptr,
    float* __restrict__ out, int n, int ostr, int accum,
    double* __restrict__ statsbuf, int sqoff)
{
    float s1 = 0.f, s2 = 0.f;
    int total = n * CSTR;
    for (int idx = blockIdx.x * 256 + threadIdx.x; idx < total; idx += gridDim.x * 256) {
        int o = idx / CSTR, c = idx % CSTR;
        int a = ptr[o], b = ptr[o + 1];
        float acc = accum ? out[(size_t)o * ostr + c] : 0.f;
        for (int s = a; s < b; ++s) acc += contrib[(size_t)s * CSTR + c];
        out[(size_t)o * ostr + c] = acc;
        if (STATS) { s1 += acc; s2 += acc * acc; }
    }
    if constexpr (STATS) {
        __shared__ double l1[256], l2[256];
        l1[threadIdx.x] = (double)s1; l2[threadIdx.x] = (double)s2;
        __syncthreads();
        for (int off = 128; off >= CSTR; off >>= 1) {
            if (threadIdx.x < (unsigned)off) {
                l1[threadIdx.x] += l1[threadIdx.x + off];
                l2[threadIdx.x] += l2[threadIdx.x + off];
            }
            __syncthreads();
        }
        if (threadIdx.x < CSTR) {
            atomicAdd(&statsbuf[threadIdx.x], l1[threadIdx.x]);
            atomicAdd(&statsbuf[sqoff + threadIdx.x], l2[threadIdx.x]);
        }
    }
}

// ---------------- BN helpers (fp64 stats) ----------------
template <int C>
__global__ __launch_bounds__(256) void make_scsh(
    const double* __restrict__ sums, const float* __restrict__ g,
    const float* __restrict__ b, float* __restrict__ sc, float* __restrict__ sh,
    double inv_n)
{
    int c = threadIdx.x;
    if (c < C) {
        double mean = sums[c] * inv_n;
        double var  = sums[C + c] * inv_n - mean * mean;
        float s = g[c] * (float)(1.0 / sqrt(var + (double)EPSc));
        sc[c] = s;
        sh[c] = b[c] - (float)mean * s;
    }
}

template <int C>
__global__ __launch_bounds__(256) void bn_apply_relu_kernel(
    float* __restrict__ x, int n, const double* __restrict__ sums,
    const float* __restrict__ g, const float* __restrict__ b)
{
    const int c = threadIdx.x % C;
    const double inv_n = 1.0 / (double)n;
    double mean = sums[c] * inv_n;
    double var  = sums[C + c] * inv_n - mean * mean;
    float scale = g[c] * (float)(1.0 / sqrt(var + (double)EPSc));
    float shift = b[c] - (float)mean * scale;
    size_t total = (size_t)n * C;
    size_t stride = (size_t)gridDim.x * 256;
    for (size_t i = (size_t)blockIdx.x * 256 + threadIdx.x; i < total; i += stride)
        x[i] = fmaxf(x[i] * scale + shift, 0.f);
}

// ---------------- host-side helpers ----------------
struct Plan { int q, nch; };

static Plan make_plan(long long tot_elems, int K, long long cap, int maxch)
{
    if (cap < 1) cap = 1;
    long long nch0 = (tot_elems + cap - 1) / cap;
    if (nch0 < 1) nch0 = 1;
    if (nch0 > K) nch0 = K;
    int q = (int)((K + nch0 - 1) / nch0);
    int nch = (K + q - 1) / q;
    if (nch > maxch) { q = (K + maxch - 1) / maxch; nch = (K + q - 1) / q; }
    return { q, nch };
}

static void build_csr2d(const int* iout, int* rank, int* bins, int* ptr, int* bsums,
                        int E, int M, int q, int nch, int stride, hipStream_t s)
{
    hipMemsetAsync(bins, 0, (size_t)nch * stride * sizeof(int), s);
    int gb = std::min(2048, (E + 255) / 256);
    hipLaunchKernelGGL(rank2d_kernel, dim3(gb), dim3(256), 0, s, iout, rank, bins, E, M, q, stride);
    int totalbins = nch * stride, nb = totalbins / 1024, bpc = stride / 1024;
    hipLaunchKernelGGL(scan1, dim3(nb), dim3(256), 0, s, bins, ptr, bsums, totalbins);
    hipLaunchKernelGGL(scan2s, dim3(1), dim3(64), 0, s, bsums, bpc, nch);
    hipLaunchKernelGGL(scan3, dim3(nb), dim3(256), 0, s, ptr, bsums, totalbins);
}

// One full layer (no cout split): k-chunked as needed.
template <int CIN, int CINC, int COUT, int TP, int TC, int GMODE, bool STATS>
static void run_layer(const float* feats, const float* W,
                      const int* iin, const int* iout, float* outp,
                      int M, int K, int n_out, int stride, int maxch,
                      int* bins, int* ptr, int* bsums, int* rank, float* contrib,
                      long long cap, const float* sc, const float* sh,
                      double* statsbuf, hipStream_t s)
{
    constexpr int NCG = COUT / TC;
    constexpr int PP  = (256 / NCG) * TP;
    Plan pl = make_plan((long long)K * M * COUT, K, cap, maxch);
    build_csr2d(iout, rank, bins, ptr, bsums, K * M, M, pl.q, pl.nch, stride, s);
    for (int ch = 0; ch < pl.nch; ++ch) {
        int k0 = ch * pl.q;
        int qc = std::min(pl.q, K - k0);
        dim3 g((M + PP - 1) / PP, qc);
        hipLaunchKernelGGL((phaseA8<CIN, CINC, COUT, COUT, TP, TC, GMODE>), g, dim3(256), 0, s,
                           feats, W + (size_t)k0 * CIN * COUT,
                           iin + (size_t)k0 * M, iout + (size_t)k0 * M,
                           ptr + (size_t)ch * stride, rank + (size_t)k0 * M,
                           contrib, M, sc, sh);
        bool last = (ch == pl.nch - 1);
        if (STATS && last)
            hipLaunchKernelGGL((phaseB8<COUT, true>), dim3(2048), dim3(256), 0, s,
                               contrib, ptr + (size_t)ch * stride, outp, n_out, COUT,
                               ch ? 1 : 0, statsbuf, COUT);
        else
            hipLaunchKernelGGL((phaseB8<COUT, false>), dim3(2048), dim3(256), 0, s,
                               contrib, ptr + (size_t)ch * stride, outp, n_out, COUT,
                               ch ? 1 : 0, (double*)nullptr, 0);
    }
}

extern "C" void kernel_launch(void* const* d_in, const int* in_sizes, int n_in,
                              void* d_out, int out_size, void* d_ws, size_t ws_size,
                              hipStream_t stream)
{
    const float* x_feats = (const float*)d_in[0];
    const float* w1a = (const float*)d_in[1];
    const float* w1b = (const float*)d_in[2];
    const float* w1c = (const float*)d_in[3];
    const float* w2  = (const float*)d_in[4];
    const float* w3a = (const float*)d_in[5];
    const float* w3b = (const float*)d_in[6];
    const float* bn1b_g = (const float*)d_in[7];
    const float* bn1b_b = (const float*)d_in[8];
    const float* bn1c_g = (const float*)d_in[9];
    const float* bn1c_b = (const float*)d_in[10];
    const float* bn3a_g = (const float*)d_in[11];
    const float* bn3a_b = (const float*)d_in[12];
    const float* bn3b_g = (const float*)d_in[13];
    const float* bn3b_b = (const float*)d_in[14];
    const int* km1a_in  = (const int*)d_in[15];
    const int* km1a_out = (const int*)d_in[16];
    const int* km1b_in  = (const int*)d_in[17];
    const int* km1b_out = (const int*)d_in[18];
    const int* km1c_in  = (const int*)d_in[19];
    const int* km1c_out = (const int*)d_in[20];
    const int* km2_in   = (const int*)d_in[21];
    const int* km2_out  = (const int*)d_in[22];
    const int* km3a_in  = (const int*)d_in[23];
    const int* km3a_out = (const int*)d_in[24];
    const int* km3b_in  = (const int*)d_in[25];
    const int* km3b_out = (const int*)d_in[26];

    float* out  = (float*)d_out;
    float* x_e1 = out;                       // [N1,32]
    float* x_e2 = out + (size_t)N1c * 32;    // [N2,256]

    // ---- workspace layout (float-element offsets, 16B-aligned) ----
    float* ws = (float*)d_ws;
    float*  poolA  = ws;                        // 10,240,000 (h1 -> h3)
    float*  poolB  = poolA + 10240000;          //  5,120,000 (h2 -> h2b)
    double* dstats = (double*)(poolB + 5120000);//  2,048 doubles (4 layers x 512)
    float*  scsh   = (float*)(dstats + 2048);   //  1,024
    int*    bins   = (int*)(scsh + 1024);       //  819,200
    int*    ptr    = bins + 819200;             //  819,200
    int*    bsums  = ptr + 819200;              //  1,024
    int*    rank   = bsums + 1024;              //  2,500,000
    float*  contrib = (float*)(rank + 2500000);
    const long long FIXED = 10240000LL + 5120000 + 4096 + 1024
                          + 819200 + 819200 + 1024 + 2500000;
    long long cap = (long long)(ws_size / 4) - FIXED - 32;
    if (cap < 1) cap = 1;

    float* h1  = poolA;   // [N1,32]
    float* h3  = poolA;   // [N2,128] (h1 dead by then)
    float* h2  = poolB;   // [N1,32]
    float* h2b = poolB;   // [N2,64]  (h2 dead by then)

    double* dst1b = dstats;
    double* dst1c = dstats + 512;
    double* dst3a = dstats + 1024;
    double* dst3b = dstats + 1536;
    float* sc1b = scsh,       *sh1b = scsh + 32;
    float* sc3a = scsh + 256, *sh3a = scsh + 384;

    hipMemsetAsync(dstats, 0, 2048 * sizeof(double), stream);

    // ---- conv1a (1->32, K=125) + ReLU: scatter (val,k) + W-in-LDS reduce ----
    {
        build_csr2d(km1a_out, rank, bins, ptr, bsums, 125 * 20000, 20000, 125, 1,
                    STRIDE_N1, stream);
        hipLaunchKernelGGL(scatter_1a, dim3(2048), dim3(256), 0, stream,
                           x_feats, km1a_in, km1a_out, ptr, rank, (float2*)contrib,
                           125 * 20000, 20000);
        hipLaunchKernelGGL(phaseB_1a, dim3(2048), dim3(256), 0, stream,
                           (const float2*)contrib, ptr, w1a, h1, N1c);
    }

    // ---- conv1b (32->32, K=125): raw out + fp64 stats; BN fused at next gather
    run_layer<32, 16, 32, 8, 4, 0, true>(h1, w1b, km1b_in, km1b_out, h2, 20000, 125, N1c,
                                         STRIDE_N1, 8, bins, ptr, bsums, rank, contrib,
                                         cap, nullptr, nullptr, dst1b, stream);
    hipLaunchKernelGGL((make_scsh<32>), dim3(1), dim3(256), 0, stream,
                       dst1b, bn1b_g, bn1b_b, sc1b, sh1b, 1.0 / N1c);

    // ---- conv1c (32->32, K=125): BN(h2)+ReLU fused at gather; x_e1 raw + stats
    run_layer<32, 16, 32, 8, 4, 2, true>(h2, w1c, km1c_in, km1c_out, x_e1, 20000, 125, N1c,
                                         STRIDE_N1, 8, bins, ptr, bsums, rank, contrib,
                                         cap, sc1b, sh1b, dst1c, stream);
    hipLaunchKernelGGL((bn_apply_relu_kernel<32>), dim3(2048), dim3(256), 0, stream,
                       x_e1, N1c, dst1c, bn1c_g, bn1c_b);

    // ---- conv2 (32->64, K=27): plain, no activation ----
    run_layer<32, 16, 64, 8, 8, 0, false>(x_e1, w2, km2_in, km2_out, h2b, 30000, 27, N2c,
                                          STRIDE_N2, 10, bins, ptr, bsums, rank, contrib,
                                          cap, nullptr, nullptr, nullptr, stream);

    // ---- conv3a (64->128, K=27): raw out + stats; BN fused at conv3b gather
    run_layer<64, 32, 128, 8, 8, 0, true>(h2b, w3a, km3a_in, km3a_out, h3, 20000, 27, N2c,
                                          STRIDE_N2, 10, bins, ptr, bsums, rank, contrib,
                                          cap, nullptr, nullptr, dst3a, stream);
    hipLaunchKernelGGL((make_scsh<128>), dim3(1), dim3(256), 0, stream,
                       dst3a, bn3a_g, bn3a_b, sc3a, sh3a, 1.0 / N2c);

    // ---- conv3b (128->256, K=27): cout-split into two 128-halves ----
    // One CSR for the layer; per half: phaseA (BN(h3)+ReLU fused) + single phaseB.
    {
        const int M = 20000, K = 27;
        Plan pl = make_plan((long long)K * M * 128, K, cap, 10);
        build_csr2d(km3b_out, rank, bins, ptr, bsums, K * M, M, pl.q, pl.nch,
                    STRIDE_N2, stream);
        constexpr int PP = (256 / (128 / 8)) * 8;   // 128 pairs per block
        for (int half = 0; half < 2; ++half) {
            for (int ch = 0; ch < pl.nch; ++ch) {
                int k0 = ch * pl.q;
                int qc = std::min(pl.q, K - k0);
                dim3 g((M + PP - 1) / PP, qc);
                hipLaunchKernelGGL((phaseA8<128, 32, 128, 256, 8, 8, 2>), g, dim3(256), 0, stream,
                                   h3, w3b + half * 128 + (size_t)k0 * 128 * 256,
                                   km3b_in + (size_t)k0 * M, km3b_out + (size_t)k0 * M,
                                   ptr + (size_t)ch * STRIDE_N2, rank + (size_t)k0 * M,
                                   contrib, M, sc3a, sh3a);
                bool last = (ch == pl.nch - 1);
                if (last)
                    hipLaunchKernelGGL((phaseB8<128, true>), dim3(2048), dim3(256), 0, stream,
                                       contrib, ptr + (size_t)ch * STRIDE_N2,
                                       x_e2 + half * 128, N2c, 256, ch ? 1 : 0,
                                       dst3b + half * 128, 256);
                else
                    hipLaunchKernelGGL((phaseB8<128, false>), dim3(2048), dim3(256), 0, stream,
                                       contrib, ptr + (size_t)ch * STRIDE_N2,
                                       x_e2 + half * 128, N2c, 256, ch ? 1 : 0,
                                       (double*)nullptr, 0);
            }
        }
        hipLaunchKernelGGL((bn_apply_relu_kernel<256>), dim3(2048), dim3(256), 0, stream,
                           x_e2, N2c, dst3b, bn3b_g, bn3b_b);
    }
}

// Round 3
// 2426.964 us; speedup vs baseline: 1.0206x; 1.0206x over previous
//
#include <hip/hip_runtime.h>
#include <cstdint>
#include <algorithm>

// ---------------- problem constants ----------------
#define N1c 100000
#define N2c 80000
#define EPSc 1e-5f
#define STRIDE_N1 102400   // 100 blocks of 1024 (>= N1+1 bins)
#define STRIDE_N2 81920    // 80 blocks of 1024  (>= N2+1 bins)

// ---------------- CSR build: one pass for ALL k-chunks of a layer ----------
__global__ __launch_bounds__(256) void rank2d_kernel(
    const int* __restrict__ out_idx, int* __restrict__ rank,
    int* __restrict__ bins, int E, int M, int q, int stride)
{
    for (int e = blockIdx.x * 256 + threadIdx.x; e < E; e += gridDim.x * 256) {
        int chunk = (e / M) / q;
        rank[e] = atomicAdd(&bins[chunk * stride + out_idx[e]], 1);
    }
}

__global__ __launch_bounds__(256) void scan1(
    const int* __restrict__ bins, int* __restrict__ ptr,
    int* __restrict__ bsums, int n)
{
    __shared__ int lds[256];
    int base = blockIdx.x * 1024;
    int v[4]; int t = 0;
    #pragma unroll
    for (int i = 0; i < 4; ++i) {
        int idx = base + threadIdx.x * 4 + i;
        v[i] = idx < n ? bins[idx] : 0;
        t += v[i];
    }
    lds[threadIdx.x] = t; __syncthreads();
    for (int off = 1; off < 256; off <<= 1) {
        int x = threadIdx.x >= off ? lds[threadIdx.x - off] : 0;
        __syncthreads();
        lds[threadIdx.x] += x;
        __syncthreads();
    }
    int run = lds[threadIdx.x] - t;
    if (threadIdx.x == 255) bsums[blockIdx.x] = lds[255];
    #pragma unroll
    for (int i = 0; i < 4; ++i) {
        int idx = base + threadIdx.x * 4 + i;
        if (idx < n) ptr[idx] = run;
        run += v[i];
    }
}

// serial exclusive scan of block sums, carry reset at chunk boundaries
__global__ __launch_bounds__(64) void scan2s(
    int* __restrict__ bsums, int bpc, int nch)
{
    int c = threadIdx.x;
    if (c < nch) {
        int run = 0;
        for (int i = 0; i < bpc; ++i) {
            int idx = c * bpc + i;
            int t = bsums[idx]; bsums[idx] = run; run += t;
        }
    }
}

__global__ __launch_bounds__(256) void scan3(
    int* __restrict__ ptr, const int* __restrict__ bsums, int n)
{
    int idx = blockIdx.x * 1024 + threadIdx.x * 4;
    int add = bsums[blockIdx.x];
    #pragma unroll
    for (int i = 0; i < 4; ++i)
        if (idx + i < n) ptr[idx + i] += add;
}

// ---------------- conv1a special: scatter (x_val, k) 8B per edge ----------
__global__ __launch_bounds__(256) void scatter_1a(
    const float* __restrict__ x, const int* __restrict__ iin,
    const int* __restrict__ iout, const int* __restrict__ ptr,
    const int* __restrict__ rank, float2* __restrict__ payload, int E, int M)
{
    for (int e = blockIdx.x * 256 + threadIdx.x; e < E; e += gridDim.x * 256) {
        int k = e / M;
        float2 p; p.x = x[iin[e]]; p.y = __int_as_float(k);
        payload[ptr[iout[e]] + rank[e]] = p;
    }
}

// out[o][c] = relu( sum_e val_e * W[k_e][c] ), W (125x32) in LDS
__global__ __launch_bounds__(256) void phaseB_1a(
    const float2* __restrict__ payload, const int* __restrict__ ptr,
    const float* __restrict__ W, float* __restrict__ out, int n)
{
    __shared__ float Wl[125 * 32];
    for (int i = threadIdx.x; i < 125 * 32; i += 256) Wl[i] = W[i];
    __syncthreads();
    int total = n * 32;
    for (int idx = blockIdx.x * 256 + threadIdx.x; idx < total; idx += gridDim.x * 256) {
        int o = idx >> 5, c = idx & 31;
        int s0 = ptr[o], s1 = ptr[o + 1];
        float acc = 0.f;
        for (int s = s0; s < s1; ++s) {
            float2 p = payload[s];
            acc = fmaf(p.x, Wl[(__float_as_int(p.y) << 5) + c], acc);
        }
        out[idx] = fmaxf(acc, 0.f);
    }
}

// ---------------- Phase A: tiled gather-GEMM, 8xTC register tiles ---------
// Thread tile = TP pairs x TC couts. W row stride WST (>=CTILE for cout-split).
// GMODE: 0 = plain gather, 2 = BN(scale/shift)+ReLU at gather.
// CINC tuning: pick smallest LDS footprint ONLY where LDS binds occupancy
// (conv3: ft is [CINC][132]). conv1/conv2 have PP=256 -> ft[CINC][260]
// dominates and NCH>1 only adds barriers: keep CINC=32 there.
// Wl stores column-group-permuted rows: float4 chunk (cg,g) lives at column
// (g*NCG+cg)*4 so a wave's wv read covers 64 consecutive dwords
// (2 lanes/bank = conflict-free) instead of 16 chunks at 32B stride (4-way).
template <int CIN, int CINC, int CTILE, int WST, int TP, int TC, int GMODE>
__global__ __launch_bounds__(256) void phaseA8(
    const float* __restrict__ feats, const float* __restrict__ W,
    const int* __restrict__ in_idx, const int* __restrict__ out_idx,
    const int* __restrict__ ptr, const int* __restrict__ rank,
    float* __restrict__ contrib, int M,
    const float* __restrict__ sc, const float* __restrict__ sh)
{
    constexpr int NCG = CTILE / TC;      // cout groups
    constexpr int PPG = 256 / NCG;       // pair groups
    constexpr int PP  = PPG * TP;        // pairs per block
    constexpr int NCH  = CIN / CINC;
    constexpr int LOADERS = 256 / PP;
    constexpr int SITER = CINC / 4 / LOADERS;
    constexpr int FTS = PP + 4;          // multiple of 4
    static_assert(SITER >= 1, "CINC too small for loader layout");

    const int k = blockIdx.y;
    __shared__ float Wl[CINC][CTILE];
    __shared__ float ft[CINC][FTS];
    __shared__ int sslot[PP];

    const int cg = threadIdx.x % NCG;
    const int pg = threadIdx.x / NCG;
    const int p0 = pg * TP;
    const int pl = threadIdx.x % PP;
    const int ll = threadIdx.x / PP;

    const int* iin  = in_idx  + (size_t)k * M;
    const int* iout = out_idx + (size_t)k * M;
    const int* rk   = rank    + (size_t)k * M;
    const float* Wk = W + (size_t)k * CIN * WST;

    for (int base = blockIdx.x * PP; base < M; base += gridDim.x * PP) {
        float acc[TP][TC];
        #pragma unroll
        for (int p = 0; p < TP; ++p)
            #pragma unroll
            for (int c = 0; c < TC; ++c) acc[p][c] = 0.f;

        #pragma unroll
        for (int ch = 0; ch < NCH; ++ch) {
            __syncthreads();
            // stage W chunk, column-group permuted (restaged per chunk)
            for (int i = threadIdx.x; i < CINC * (CTILE / 4); i += 256) {
                int j = i / (CTILE / 4), q = i % (CTILE / 4);
                int gq = q % (TC / 4);          // g of this float4 chunk
                int cq = q / (TC / 4);          // cg of this chunk
                int pq = gq * NCG + cq;         // permuted chunk position
                *(float4*)&Wl[j][pq * 4] =
                    *(const float4*)(Wk + (size_t)(ch * CINC + j) * WST + q * 4);
            }
            int p = base + pl;
            if (p < M) {
                if (ch == 0 && threadIdx.x < PP)
                    sslot[pl] = ptr[iout[p]] + rk[p];
                const float* fr = feats + (size_t)iin[p] * CIN + ch * CINC;
                #pragma unroll
                for (int i = 0; i < SITER; ++i) {
                    int j4 = (ll + i * LOADERS) * 4;
                    float4 v = *(const float4*)(fr + j4);
                    if (GMODE == 2) {
                        float4 s4 = *(const float4*)(sc + ch * CINC + j4);
                        float4 h4 = *(const float4*)(sh + ch * CINC + j4);
                        v.x = fmaxf(fmaf(v.x, s4.x, h4.x), 0.f);
                        v.y = fmaxf(fmaf(v.y, s4.y, h4.y), 0.f);
                        v.z = fmaxf(fmaf(v.z, s4.z, h4.z), 0.f);
                        v.w = fmaxf(fmaf(v.w, s4.w, h4.w), 0.f);
                    }
                    ft[j4 + 0][pl] = v.x;
                    ft[j4 + 1][pl] = v.y;
                    ft[j4 + 2][pl] = v.z;
                    ft[j4 + 3][pl] = v.w;
                }
            }
            __syncthreads();

            #pragma unroll 4
            for (int j = 0; j < CINC; ++j) {
                float fv[TP], wv[TC];
                #pragma unroll
                for (int g = 0; g < TP / 4; ++g)
                    *(float4*)&fv[g * 4] = *(const float4*)&ft[j][p0 + g * 4];
                #pragma unroll
                for (int g = 0; g < TC / 4; ++g)
                    *(float4*)&wv[g * 4] = *(const float4*)&Wl[j][(g * NCG + cg) * 4];
                #pragma unroll
                for (int p = 0; p < TP; ++p)
                    #pragma unroll
                    for (int c = 0; c < TC; ++c)
                        acc[p][c] = fmaf(fv[p], wv[c], acc[p][c]);
            }
        }

        #pragma unroll
        for (int q = 0; q < TP; ++q) {
            if (base + p0 + q < M) {
                size_t s = (size_t)sslot[p0 + q];
                #pragma unroll
                for (int g = 0; g < TC / 4; ++g) {
                    float4 o4;
                    o4.x = acc[q][g * 4 + 0]; o4.y = acc[q][g * 4 + 1];
                    o4.z = acc[q][g * 4 + 2]; o4.w = acc[q][g * 4 + 3];
                    *(float4*)&contrib[s * CTILE + cg * TC + g * 4] = o4;
                }
            }
        }
    }
}

// ---------------- Phase B: segmented sum (+optional fused fp64 BN stats) ---
template <int CSTR, bool STATS>
__global__ __launch_bounds__(256) void phaseB8(
    const float* __restrict__ contrib, const int* __restrict__ ptr,
    float* __restrict__ out, int n, int ostr, int accum,
    double* __restrict__ statsbuf, int sqoff)
{
    float s1 = 0.f, s2 = 0.f;
    int total = n * CSTR;
    for (int idx = blockIdx.x * 256 + threadIdx.x; idx < total; idx += gridDim.x * 256) {
        int o = idx / CSTR, c = idx % CSTR;
        int a = ptr[o], b = ptr[o + 1];
        float acc = accum ? out[(size_t)o * ostr + c] : 0.f;
        for (int s = a; s < b; ++s) acc += contrib[(size_t)s * CSTR + c];
        out[(size_t)o * ostr + c] = acc;
        if (STATS) { s1 += acc; s2 += acc * acc; }
    }
    if constexpr (STATS) {
        __shared__ double l1[256], l2[256];
        l1[threadIdx.x] = (double)s1; l2[threadIdx.x] = (double)s2;
        __syncthreads();
        for (int off = 128; off >= CSTR; off >>= 1) {
            if (threadIdx.x < (unsigned)off) {
                l1[threadIdx.x] += l1[threadIdx.x + off];
                l2[threadIdx.x] += l2[threadIdx.x + off];
            }
            __syncthreads();
        }
        if (threadIdx.x < CSTR) {
            atomicAdd(&statsbuf[threadIdx.x], l1[threadIdx.x]);
            atomicAdd(&statsbuf[sqoff + threadIdx.x], l2[threadIdx.x]);
        }
    }
}

// ---------------- BN helpers (fp64 stats) ----------------
template <int C>
__global__ __launch_bounds__(256) void make_scsh(
    const double* __restrict__ sums, const float* __restrict__ g,
    const float* __restrict__ b, float* __restrict__ sc, float* __restrict__ sh,
    double inv_n)
{
    int c = threadIdx.x;
    if (c < C) {
        double mean = sums[c] * inv_n;
        double var  = sums[C + c] * inv_n - mean * mean;
        float s = g[c] * (float)(1.0 / sqrt(var + (double)EPSc));
        sc[c] = s;
        sh[c] = b[c] - (float)mean * s;
    }
}

template <int C>
__global__ __launch_bounds__(256) void bn_apply_relu_kernel(
    float* __restrict__ x, int n, const double* __restrict__ sums,
    const float* __restrict__ g, const float* __restrict__ b)
{
    const int c = threadIdx.x % C;
    const double inv_n = 1.0 / (double)n;
    double mean = sums[c] * inv_n;
    double var  = sums[C + c] * inv_n - mean * mean;
    float scale = g[c] * (float)(1.0 / sqrt(var + (double)EPSc));
    float shift = b[c] - (float)mean * scale;
    size_t total = (size_t)n * C;
    size_t stride = (size_t)gridDim.x * 256;
    for (size_t i = (size_t)blockIdx.x * 256 + threadIdx.x; i < total; i += stride)
        x[i] = fmaxf(x[i] * scale + shift, 0.f);
}

// ---------------- host-side helpers ----------------
struct Plan { int q, nch; };

static Plan make_plan(long long tot_elems, int K, long long cap, int maxch)
{
    if (cap < 1) cap = 1;
    long long nch0 = (tot_elems + cap - 1) / cap;
    if (nch0 < 1) nch0 = 1;
    if (nch0 > K) nch0 = K;
    int q = (int)((K + nch0 - 1) / nch0);
    int nch = (K + q - 1) / q;
    if (nch > maxch) { q = (K + maxch - 1) / maxch; nch = (K + q - 1) / q; }
    return { q, nch };
}

static void build_csr2d(const int* iout, int* rank, int* bins, int* ptr, int* bsums,
                        int E, int M, int q, int nch, int stride, hipStream_t s)
{
    hipMemsetAsync(bins, 0, (size_t)nch * stride * sizeof(int), s);
    int gb = std::min(2048, (E + 255) / 256);
    hipLaunchKernelGGL(rank2d_kernel, dim3(gb), dim3(256), 0, s, iout, rank, bins, E, M, q, stride);
    int totalbins = nch * stride, nb = totalbins / 1024, bpc = stride / 1024;
    hipLaunchKernelGGL(scan1, dim3(nb), dim3(256), 0, s, bins, ptr, bsums, totalbins);
    hipLaunchKernelGGL(scan2s, dim3(1), dim3(64), 0, s, bsums, bpc, nch);
    hipLaunchKernelGGL(scan3, dim3(nb), dim3(256), 0, s, ptr, bsums, totalbins);
}

// One full layer (no cout split): k-chunked as needed.
template <int CIN, int CINC, int COUT, int TP, int TC, int GMODE, bool STATS>
static void run_layer(const float* feats, const float* W,
                      const int* iin, const int* iout, float* outp,
                      int M, int K, int n_out, int stride, int maxch,
                      int* bins, int* ptr, int* bsums, int* rank, float* contrib,
                      long long cap, const float* sc, const float* sh,
                      double* statsbuf, hipStream_t s)
{
    constexpr int NCG = COUT / TC;
    constexpr int PP  = (256 / NCG) * TP;
    Plan pl = make_plan((long long)K * M * COUT, K, cap, maxch);
    build_csr2d(iout, rank, bins, ptr, bsums, K * M, M, pl.q, pl.nch, stride, s);
    for (int ch = 0; ch < pl.nch; ++ch) {
        int k0 = ch * pl.q;
        int qc = std::min(pl.q, K - k0);
        dim3 g((M + PP - 1) / PP, qc);
        hipLaunchKernelGGL((phaseA8<CIN, CINC, COUT, COUT, TP, TC, GMODE>), g, dim3(256), 0, s,
                           feats, W + (size_t)k0 * CIN * COUT,
                           iin + (size_t)k0 * M, iout + (size_t)k0 * M,
                           ptr + (size_t)ch * stride, rank + (size_t)k0 * M,
                           contrib, M, sc, sh);
        bool last = (ch == pl.nch - 1);
        if (STATS && last)
            hipLaunchKernelGGL((phaseB8<COUT, true>), dim3(2048), dim3(256), 0, s,
                               contrib, ptr + (size_t)ch * stride, outp, n_out, COUT,
                               ch ? 1 : 0, statsbuf, COUT);
        else
            hipLaunchKernelGGL((phaseB8<COUT, false>), dim3(2048), dim3(256), 0, s,
                               contrib, ptr + (size_t)ch * stride, outp, n_out, COUT,
                               ch ? 1 : 0, (double*)nullptr, 0);
    }
}

extern "C" void kernel_launch(void* const* d_in, const int* in_sizes, int n_in,
                              void* d_out, int out_size, void* d_ws, size_t ws_size,
                              hipStream_t stream)
{
    const float* x_feats = (const float*)d_in[0];
    const float* w1a = (const float*)d_in[1];
    const float* w1b = (const float*)d_in[2];
    const float* w1c = (const float*)d_in[3];
    const float* w2  = (const float*)d_in[4];
    const float* w3a = (const float*)d_in[5];
    const float* w3b = (const float*)d_in[6];
    const float* bn1b_g = (const float*)d_in[7];
    const float* bn1b_b = (const float*)d_in[8];
    const float* bn1c_g = (const float*)d_in[9];
    const float* bn1c_b = (const float*)d_in[10];
    const float* bn3a_g = (const float*)d_in[11];
    const float* bn3a_b = (const float*)d_in[12];
    const float* bn3b_g = (const float*)d_in[13];
    const float* bn3b_b = (const float*)d_in[14];
    const int* km1a_in  = (const int*)d_in[15];
    const int* km1a_out = (const int*)d_in[16];
    const int* km1b_in  = (const int*)d_in[17];
    const int* km1b_out = (const int*)d_in[18];
    const int* km1c_in  = (const int*)d_in[19];
    const int* km1c_out = (const int*)d_in[20];
    const int* km2_in   = (const int*)d_in[21];
    const int* km2_out  = (const int*)d_in[22];
    const int* km3a_in  = (const int*)d_in[23];
    const int* km3a_out = (const int*)d_in[24];
    const int* km3b_in  = (const int*)d_in[25];
    const int* km3b_out = (const int*)d_in[26];

    float* out  = (float*)d_out;
    float* x_e1 = out;                       // [N1,32]
    float* x_e2 = out + (size_t)N1c * 32;    // [N2,256]

    // ---- workspace layout (float-element offsets, 16B-aligned) ----
    float* ws = (float*)d_ws;
    float*  poolA  = ws;                        // 10,240,000 (h1 -> h3)
    float*  poolB  = poolA + 10240000;          //  5,120,000 (h2 -> h2b)
    double* dstats = (double*)(poolB + 5120000);//  2,048 doubles (4 layers x 512)
    float*  scsh   = (float*)(dstats + 2048);   //  1,024
    int*    bins   = (int*)(scsh + 1024);       //  819,200
    int*    ptr    = bins + 819200;             //  819,200
    int*    bsums  = ptr + 819200;              //  1,024
    int*    rank   = bsums + 1024;              //  2,500,000
    float*  contrib = (float*)(rank + 2500000);
    const long long FIXED = 10240000LL + 5120000 + 4096 + 1024
                          + 819200 + 819200 + 1024 + 2500000;
    long long cap = (long long)(ws_size / 4) - FIXED - 32;
    if (cap < 1) cap = 1;

    float* h1  = poolA;   // [N1,32]
    float* h3  = poolA;   // [N2,128] (h1 dead by then)
    float* h2  = poolB;   // [N1,32]
    float* h2b = poolB;   // [N2,64]  (h2 dead by then)

    double* dst1b = dstats;
    double* dst1c = dstats + 512;
    double* dst3a = dstats + 1024;
    double* dst3b = dstats + 1536;
    float* sc1b = scsh,       *sh1b = scsh + 32;
    float* sc3a = scsh + 256, *sh3a = scsh + 384;

    hipMemsetAsync(dstats, 0, 2048 * sizeof(double), stream);

    // ---- conv1a (1->32, K=125) + ReLU: scatter (val,k) + W-in-LDS reduce ----
    {
        build_csr2d(km1a_out, rank, bins, ptr, bsums, 125 * 20000, 20000, 125, 1,
                    STRIDE_N1, stream);
        hipLaunchKernelGGL(scatter_1a, dim3(2048), dim3(256), 0, stream,
                           x_feats, km1a_in, km1a_out, ptr, rank, (float2*)contrib,
                           125 * 20000, 20000);
        hipLaunchKernelGGL(phaseB_1a, dim3(2048), dim3(256), 0, stream,
                           (const float2*)contrib, ptr, w1a, h1, N1c);
    }

    // ---- conv1b (32->32, K=125): raw out + fp64 stats; BN fused at next gather
    run_layer<32, 32, 32, 8, 4, 0, true>(h1, w1b, km1b_in, km1b_out, h2, 20000, 125, N1c,
                                         STRIDE_N1, 8, bins, ptr, bsums, rank, contrib,
                                         cap, nullptr, nullptr, dst1b, stream);
    hipLaunchKernelGGL((make_scsh<32>), dim3(1), dim3(256), 0, stream,
                       dst1b, bn1b_g, bn1b_b, sc1b, sh1b, 1.0 / N1c);

    // ---- conv1c (32->32, K=125): BN(h2)+ReLU fused at gather; x_e1 raw + stats
    run_layer<32, 32, 32, 8, 4, 2, true>(h2, w1c, km1c_in, km1c_out, x_e1, 20000, 125, N1c,
                                         STRIDE_N1, 8, bins, ptr, bsums, rank, contrib,
                                         cap, sc1b, sh1b, dst1c, stream);
    hipLaunchKernelGGL((bn_apply_relu_kernel<32>), dim3(2048), dim3(256), 0, stream,
                       x_e1, N1c, dst1c, bn1c_g, bn1c_b);

    // ---- conv2 (32->64, K=27): plain, no activation ----
    run_layer<32, 32, 64, 8, 8, 0, false>(x_e1, w2, km2_in, km2_out, h2b, 30000, 27, N2c,
                                          STRIDE_N2, 10, bins, ptr, bsums, rank, contrib,
                                          cap, nullptr, nullptr, nullptr, stream);

    // ---- conv3a (64->128, K=27): raw out + stats; BN fused at conv3b gather
    run_layer<64, 16, 128, 8, 8, 0, true>(h2b, w3a, km3a_in, km3a_out, h3, 20000, 27, N2c,
                                          STRIDE_N2, 10, bins, ptr, bsums, rank, contrib,
                                          cap, nullptr, nullptr, dst3a, stream);
    hipLaunchKernelGGL((make_scsh<128>), dim3(1), dim3(256), 0, stream,
                       dst3a, bn3a_g, bn3a_b, sc3a, sh3a, 1.0 / N2c);

    // ---- conv3b (128->256, K=27): cout-split into two 128-halves ----
    // One CSR for the layer; per half: phaseA (BN(h3)+ReLU fused) + single phaseB.
    {
        const int M = 20000, K = 27;
        Plan pl = make_plan((long long)K * M * 128, K, cap, 10);
        build_csr2d(km3b_out, rank, bins, ptr, bsums, K * M, M, pl.q, pl.nch,
                    STRIDE_N2, stream);
        constexpr int PP = (256 / (128 / 8)) * 8;   // 128 pairs per block
        for (int half = 0; half < 2; ++half) {
            for (int ch = 0; ch < pl.nch; ++ch) {
                int k0 = ch * pl.q;
                int qc = std::min(pl.q, K - k0);
                dim3 g((M + PP - 1) / PP, qc);
                hipLaunchKernelGGL((phaseA8<128, 16, 128, 256, 8, 8, 2>), g, dim3(256), 0, stream,
                                   h3, w3b + half * 128 + (size_t)k0 * 128 * 256,
                                   km3b_in + (size_t)k0 * M, km3b_out + (size_t)k0 * M,
                                   ptr + (size_t)ch * STRIDE_N2, rank + (size_t)k0 * M,
                                   contrib, M, sc3a, sh3a);
                bool last = (ch == pl.nch - 1);
                if (last)
                    hipLaunchKernelGGL((phaseB8<128, true>), dim3(2048), dim3(256), 0, stream,
                                       contrib, ptr + (size_t)ch * STRIDE_N2,
                                       x_e2 + half * 128, N2c, 256, ch ? 1 : 0,
                                       dst3b + half * 128, 256);
                else
                    hipLaunchKernelGGL((phaseB8<128, false>), dim3(2048), dim3(256), 0, stream,
                                       contrib, ptr + (size_t)ch * STRIDE_N2,
                                       x_e2 + half * 128, N2c, 256, ch ? 1 : 0,
                                       (double*)nullptr, 0);
            }
        }
        hipLaunchKernelGGL((bn_apply_relu_kernel<256>), dim3(2048), dim3(256), 0, stream,
                           x_e2, N2c, dst3b, bn3b_g, bn3b_b);
    }
}

// Round 4
// 2201.149 us; speedup vs baseline: 1.1253x; 1.1026x over previous
//
#include <hip/hip_runtime.h>
#include <hip/hip_fp16.h>
#include <cstdint>
#include <algorithm>

// ---------------- problem constants ----------------
#define N1c 100000
#define N2c 80000
#define EPSc 1e-5f
#define STRIDE_N1 102400   // 100 blocks of 1024 (>= N1+1 bins)
#define STRIDE_N2 81920    // 80 blocks of 1024  (>= N2+1 bins)

// ---------------- CSR build: one pass for ALL k-chunks of a layer ----------
__global__ __launch_bounds__(256) void rank2d_kernel(
    const int* __restrict__ out_idx, int* __restrict__ rank,
    int* __restrict__ bins, int E, int M, int q, int stride)
{
    for (int e = blockIdx.x * 256 + threadIdx.x; e < E; e += gridDim.x * 256) {
        int chunk = (e / M) / q;
        rank[e] = atomicAdd(&bins[chunk * stride + out_idx[e]], 1);
    }
}

__global__ __launch_bounds__(256) void scan1(
    const int* __restrict__ bins, int* __restrict__ ptr,
    int* __restrict__ bsums, int n)
{
    __shared__ int lds[256];
    int base = blockIdx.x * 1024;
    int v[4]; int t = 0;
    #pragma unroll
    for (int i = 0; i < 4; ++i) {
        int idx = base + threadIdx.x * 4 + i;
        v[i] = idx < n ? bins[idx] : 0;
        t += v[i];
    }
    lds[threadIdx.x] = t; __syncthreads();
    for (int off = 1; off < 256; off <<= 1) {
        int x = threadIdx.x >= off ? lds[threadIdx.x - off] : 0;
        __syncthreads();
        lds[threadIdx.x] += x;
        __syncthreads();
    }
    int run = lds[threadIdx.x] - t;
    if (threadIdx.x == 255) bsums[blockIdx.x] = lds[255];
    #pragma unroll
    for (int i = 0; i < 4; ++i) {
        int idx = base + threadIdx.x * 4 + i;
        if (idx < n) ptr[idx] = run;
        run += v[i];
    }
}

// serial exclusive scan of block sums, carry reset at chunk boundaries
__global__ __launch_bounds__(64) void scan2s(
    int* __restrict__ bsums, int bpc, int nch)
{
    int c = threadIdx.x;
    if (c < nch) {
        int run = 0;
        for (int i = 0; i < bpc; ++i) {
            int idx = c * bpc + i;
            int t = bsums[idx]; bsums[idx] = run; run += t;
        }
    }
}

__global__ __launch_bounds__(256) void scan3(
    int* __restrict__ ptr, const int* __restrict__ bsums, int n)
{
    int idx = blockIdx.x * 1024 + threadIdx.x * 4;
    int add = bsums[blockIdx.x];
    #pragma unroll
    for (int i = 0; i < 4; ++i)
        if (idx + i < n) ptr[idx + i] += add;
}

// ---------------- conv1a special: scatter (x_val, k) 8B per edge ----------
__global__ __launch_bounds__(256) void scatter_1a(
    const float* __restrict__ x, const int* __restrict__ iin,
    const int* __restrict__ iout, const int* __restrict__ ptr,
    const int* __restrict__ rank, float2* __restrict__ payload, int E, int M)
{
    for (int e = blockIdx.x * 256 + threadIdx.x; e < E; e += gridDim.x * 256) {
        int k = e / M;
        float2 p; p.x = x[iin[e]]; p.y = __int_as_float(k);
        payload[ptr[iout[e]] + rank[e]] = p;
    }
}

// out[o][c] = relu( sum_e val_e * W[k_e][c] ), W (125x32) in LDS
__global__ __launch_bounds__(256) void phaseB_1a(
    const float2* __restrict__ payload, const int* __restrict__ ptr,
    const float* __restrict__ W, float* __restrict__ out, int n)
{
    __shared__ float Wl[125 * 32];
    for (int i = threadIdx.x; i < 125 * 32; i += 256) Wl[i] = W[i];
    __syncthreads();
    int total = n * 32;
    for (int idx = blockIdx.x * 256 + threadIdx.x; idx < total; idx += gridDim.x * 256) {
        int o = idx >> 5, c = idx & 31;
        int s0 = ptr[o], s1 = ptr[o + 1];
        float acc = 0.f;
        for (int s = s0; s < s1; ++s) {
            float2 p = payload[s];
            acc = fmaf(p.x, Wl[(__float_as_int(p.y) << 5) + c], acc);
        }
        out[idx] = fmaxf(acc, 0.f);
    }
}

// ---------------- Phase A: tiled gather-GEMM, 8xTC register tiles ---------
// Thread tile = TP pairs x TC couts. W row stride WST (>=CTILE for cout-split).
// GMODE: 0 = plain gather, 2 = BN(scale/shift)+ReLU at gather.
// CINC=32 everywhere: round-3 showed CINC=16 raised FETCH (row split into 8
// temporally-separated 64B visits) with no occupancy gain below 34KB LDS.
// Gather prefetch pipeline: chunk ch+1's feats loads issue before chunk ch's
// FMA loop, hiding random-gather latency that the barrier otherwise exposes.
// Wl stores column-group-permuted rows (chunk (cg,g) at column (g*NCG+cg)*4):
// wv reads cover 64 consecutive dwords -> 2 lanes/bank, conflict-free
// (verified round 3: SQ_LDS_BANK_CONFLICT 1.74e7 -> 2.2e6).
// Contrib is fp16: partial sums are O(0.3), ~7 summands -> quantization error
// ~2e-4 abs; halves the dominant HBM round-trip traffic.
template <int CIN, int CINC, int CTILE, int WST, int TP, int TC, int GMODE>
__global__ __launch_bounds__(256) void phaseA8(
    const float* __restrict__ feats, const float* __restrict__ W,
    const int* __restrict__ in_idx, const int* __restrict__ out_idx,
    const int* __restrict__ ptr, const int* __restrict__ rank,
    __half* __restrict__ contrib, int M,
    const float* __restrict__ sc, const float* __restrict__ sh)
{
    constexpr int NCG = CTILE / TC;      // cout groups
    constexpr int PPG = 256 / NCG;       // pair groups
    constexpr int PP  = PPG * TP;        // pairs per block
    constexpr int NCH  = CIN / CINC;
    constexpr int LOADERS = 256 / PP;
    constexpr int SITER = CINC / 4 / LOADERS;
    constexpr int FTS = PP + 4;          // multiple of 4
    static_assert(SITER >= 1, "CINC too small for loader layout");

    const int k = blockIdx.y;
    __shared__ float Wl[CINC][CTILE];
    __shared__ float ft[CINC][FTS];
    __shared__ int sslot[PP];

    const int cg = threadIdx.x % NCG;
    const int pg = threadIdx.x / NCG;
    const int p0 = pg * TP;
    const int pl = threadIdx.x % PP;
    const int ll = threadIdx.x / PP;

    const int* iin  = in_idx  + (size_t)k * M;
    const int* iout = out_idx + (size_t)k * M;
    const int* rk   = rank    + (size_t)k * M;
    const float* Wk = W + (size_t)k * CIN * WST;

    for (int base = blockIdx.x * PP; base < M; base += gridDim.x * PP) {
        float acc[TP][TC];
        #pragma unroll
        for (int p = 0; p < TP; ++p)
            #pragma unroll
            for (int c = 0; c < TC; ++c) acc[p][c] = 0.f;

        // prologue: issue chunk-0 gather into registers
        int p = base + pl;
        bool act = p < M;
        const float* fr = nullptr;
        float4 v[SITER];
        if (act) {
            fr = feats + (size_t)iin[p] * CIN;
            #pragma unroll
            for (int i = 0; i < SITER; ++i)
                v[i] = *(const float4*)(fr + (ll + i * LOADERS) * 4);
        }

        #pragma unroll
        for (int ch = 0; ch < NCH; ++ch) {
            __syncthreads();   // prev FMA done reading ft
            // stage W chunk, column-group permuted
            for (int i = threadIdx.x; i < CINC * (CTILE / 4); i += 256) {
                int j = i / (CTILE / 4), q = i % (CTILE / 4);
                int gq = q % (TC / 4);          // g of this float4 chunk
                int cq = q / (TC / 4);          // cg of this chunk
                int pq = gq * NCG + cq;         // permuted chunk position
                *(float4*)&Wl[j][pq * 4] =
                    *(const float4*)(Wk + (size_t)(ch * CINC + j) * WST + q * 4);
            }
            if (act) {
                if (ch == 0 && threadIdx.x < PP)
                    sslot[pl] = ptr[iout[p]] + rk[p];
                #pragma unroll
                for (int i = 0; i < SITER; ++i) {
                    int j4 = (ll + i * LOADERS) * 4;
                    float4 w = v[i];
                    if (GMODE == 2) {
                        float4 s4 = *(const float4*)(sc + ch * CINC + j4);
                        float4 h4 = *(const float4*)(sh + ch * CINC + j4);
                        w.x = fmaxf(fmaf(w.x, s4.x, h4.x), 0.f);
                        w.y = fmaxf(fmaf(w.y, s4.y, h4.y), 0.f);
                        w.z = fmaxf(fmaf(w.z, s4.z, h4.z), 0.f);
                        w.w = fmaxf(fmaf(w.w, s4.w, h4.w), 0.f);
                    }
                    ft[j4 + 0][pl] = w.x;
                    ft[j4 + 1][pl] = w.y;
                    ft[j4 + 2][pl] = w.z;
                    ft[j4 + 3][pl] = w.w;
                }
                if (ch + 1 < NCH) {   // prefetch next chunk (overlaps FMA below)
                    #pragma unroll
                    for (int i = 0; i < SITER; ++i)
                        v[i] = *(const float4*)(fr + (ch + 1) * CINC
                                                + (ll + i * LOADERS) * 4);
                }
            }
            __syncthreads();

            #pragma unroll 4
            for (int j = 0; j < CINC; ++j) {
                float fv[TP], wv[TC];
                #pragma unroll
                for (int g = 0; g < TP / 4; ++g)
                    *(float4*)&fv[g * 4] = *(const float4*)&ft[j][p0 + g * 4];
                #pragma unroll
                for (int g = 0; g < TC / 4; ++g)
                    *(float4*)&wv[g * 4] = *(const float4*)&Wl[j][(g * NCG + cg) * 4];
                #pragma unroll
                for (int pp = 0; pp < TP; ++pp)
                    #pragma unroll
                    for (int c = 0; c < TC; ++c)
                        acc[pp][c] = fmaf(fv[pp], wv[c], acc[pp][c]);
            }
        }

        #pragma unroll
        for (int q = 0; q < TP; ++q) {
            if (base + p0 + q < M) {
                size_t s = (size_t)sslot[p0 + q];
                #pragma unroll
                for (int g = 0; g < TC / 4; ++g) {
                    __half2 h0 = __floats2half2_rn(acc[q][g * 4 + 0], acc[q][g * 4 + 1]);
                    __half2 h1 = __floats2half2_rn(acc[q][g * 4 + 2], acc[q][g * 4 + 3]);
                    uint2 pk;
                    pk.x = *(unsigned int*)&h0;
                    pk.y = *(unsigned int*)&h1;
                    *(uint2*)&contrib[s * CTILE + cg * TC + g * 4] = pk;
                }
            }
        }
    }
}

// ---------------- Phase B: segmented sum (+optional fused fp64 BN stats) ---
template <int CSTR, bool STATS>
__global__ __launch_bounds__(256) void phaseB8(
    const __half* __restrict__ contrib, const int* __restrict__ ptr,
    float* __restrict__ out, int n, int ostr, int accum,
    double* __restrict__ statsbuf, int sqoff)
{
    float s1 = 0.f, s2 = 0.f;
    int total = n * CSTR;
    for (int idx = blockIdx.x * 256 + threadIdx.x; idx < total; idx += gridDim.x * 256) {
        int o = idx / CSTR, c = idx % CSTR;
        int a = ptr[o], b = ptr[o + 1];
        float acc = accum ? out[(size_t)o * ostr + c] : 0.f;
        for (int s = a; s < b; ++s)
            acc += __half2float(contrib[(size_t)s * CSTR + c]);
        out[(size_t)o * ostr + c] = acc;
        if (STATS) { s1 += acc; s2 += acc * acc; }
    }
    if constexpr (STATS) {
        __shared__ double l1[256], l2[256];
        l1[threadIdx.x] = (double)s1; l2[threadIdx.x] = (double)s2;
        __syncthreads();
        for (int off = 128; off >= CSTR; off >>= 1) {
            if (threadIdx.x < (unsigned)off) {
                l1[threadIdx.x] += l1[threadIdx.x + off];
                l2[threadIdx.x] += l2[threadIdx.x + off];
            }
            __syncthreads();
        }
        if (threadIdx.x < CSTR) {
            atomicAdd(&statsbuf[threadIdx.x], l1[threadIdx.x]);
            atomicAdd(&statsbuf[sqoff + threadIdx.x], l2[threadIdx.x]);
        }
    }
}

// ---------------- BN helpers (fp64 stats) ----------------
template <int C>
__global__ __launch_bounds__(256) void make_scsh(
    const double* __restrict__ sums, const float* __restrict__ g,
    const float* __restrict__ b, float* __restrict__ sc, float* __restrict__ sh,
    double inv_n)
{
    int c = threadIdx.x;
    if (c < C) {
        double mean = sums[c] * inv_n;
        double var  = sums[C + c] * inv_n - mean * mean;
        float s = g[c] * (float)(1.0 / sqrt(var + (double)EPSc));
        sc[c] = s;
        sh[c] = b[c] - (float)mean * s;
    }
}

template <int C>
__global__ __launch_bounds__(256) void bn_apply_relu_kernel(
    float* __restrict__ x, int n, const double* __restrict__ sums,
    const float* __restrict__ g, const float* __restrict__ b)
{
    const int c = threadIdx.x % C;
    const double inv_n = 1.0 / (double)n;
    double mean = sums[c] * inv_n;
    double var  = sums[C + c] * inv_n - mean * mean;
    float scale = g[c] * (float)(1.0 / sqrt(var + (double)EPSc));
    float shift = b[c] - (float)mean * scale;
    size_t total = (size_t)n * C;
    size_t stride = (size_t)gridDim.x * 256;
    for (size_t i = (size_t)blockIdx.x * 256 + threadIdx.x; i < total; i += stride)
        x[i] = fmaxf(x[i] * scale + shift, 0.f);
}

// ---------------- host-side helpers ----------------
struct Plan { int q, nch; };

static Plan make_plan(long long tot_elems, int K, long long cap, int maxch)
{
    if (cap < 1) cap = 1;
    long long nch0 = (tot_elems + cap - 1) / cap;
    if (nch0 < 1) nch0 = 1;
    if (nch0 > K) nch0 = K;
    int q = (int)((K + nch0 - 1) / nch0);
    int nch = (K + q - 1) / q;
    if (nch > maxch) { q = (K + maxch - 1) / maxch; nch = (K + q - 1) / q; }
    return { q, nch };
}

static void build_csr2d(const int* iout, int* rank, int* bins, int* ptr, int* bsums,
                        int E, int M, int q, int nch, int stride, hipStream_t s)
{
    hipMemsetAsync(bins, 0, (size_t)nch * stride * sizeof(int), s);
    int gb = std::min(2048, (E + 255) / 256);
    hipLaunchKernelGGL(rank2d_kernel, dim3(gb), dim3(256), 0, s, iout, rank, bins, E, M, q, stride);
    int totalbins = nch * stride, nb = totalbins / 1024, bpc = stride / 1024;
    hipLaunchKernelGGL(scan1, dim3(nb), dim3(256), 0, s, bins, ptr, bsums, totalbins);
    hipLaunchKernelGGL(scan2s, dim3(1), dim3(64), 0, s, bsums, bpc, nch);
    hipLaunchKernelGGL(scan3, dim3(nb), dim3(256), 0, s, ptr, bsums, totalbins);
}

// One full layer (no cout split): k-chunked as needed.
template <int CIN, int CINC, int COUT, int TP, int TC, int GMODE, bool STATS>
static void run_layer(const float* feats, const float* W,
                      const int* iin, const int* iout, float* outp,
                      int M, int K, int n_out, int stride, int maxch,
                      int* bins, int* ptr, int* bsums, int* rank, __half* contrib,
                      long long cap_f32, const float* sc, const float* sh,
                      double* statsbuf, hipStream_t s)
{
    constexpr int NCG = COUT / TC;
    constexpr int PP  = (256 / NCG) * TP;
    long long cap_h = cap_f32 * 2;   // contrib region holds half-precision elems
    Plan pl = make_plan((long long)K * M * COUT, K, cap_h, maxch);
    build_csr2d(iout, rank, bins, ptr, bsums, K * M, M, pl.q, pl.nch, stride, s);
    for (int ch = 0; ch < pl.nch; ++ch) {
        int k0 = ch * pl.q;
        int qc = std::min(pl.q, K - k0);
        dim3 g((M + PP - 1) / PP, qc);
        hipLaunchKernelGGL((phaseA8<CIN, CINC, COUT, COUT, TP, TC, GMODE>), g, dim3(256), 0, s,
                           feats, W + (size_t)k0 * CIN * COUT,
                           iin + (size_t)k0 * M, iout + (size_t)k0 * M,
                           ptr + (size_t)ch * stride, rank + (size_t)k0 * M,
                           contrib, M, sc, sh);
        bool last = (ch == pl.nch - 1);
        if (STATS && last)
            hipLaunchKernelGGL((phaseB8<COUT, true>), dim3(2048), dim3(256), 0, s,
                               contrib, ptr + (size_t)ch * stride, outp, n_out, COUT,
                               ch ? 1 : 0, statsbuf, COUT);
        else
            hipLaunchKernelGGL((phaseB8<COUT, false>), dim3(2048), dim3(256), 0, s,
                               contrib, ptr + (size_t)ch * stride, outp, n_out, COUT,
                               ch ? 1 : 0, (double*)nullptr, 0);
    }
}

extern "C" void kernel_launch(void* const* d_in, const int* in_sizes, int n_in,
                              void* d_out, int out_size, void* d_ws, size_t ws_size,
                              hipStream_t stream)
{
    const float* x_feats = (const float*)d_in[0];
    const float* w1a = (const float*)d_in[1];
    const float* w1b = (const float*)d_in[2];
    const float* w1c = (const float*)d_in[3];
    const float* w2  = (const float*)d_in[4];
    const float* w3a = (const float*)d_in[5];
    const float* w3b = (const float*)d_in[6];
    const float* bn1b_g = (const float*)d_in[7];
    const float* bn1b_b = (const float*)d_in[8];
    const float* bn1c_g = (const float*)d_in[9];
    const float* bn1c_b = (const float*)d_in[10];
    const float* bn3a_g = (const float*)d_in[11];
    const float* bn3a_b = (const float*)d_in[12];
    const float* bn3b_g = (const float*)d_in[13];
    const float* bn3b_b = (const float*)d_in[14];
    const int* km1a_in  = (const int*)d_in[15];
    const int* km1a_out = (const int*)d_in[16];
    const int* km1b_in  = (const int*)d_in[17];
    const int* km1b_out = (const int*)d_in[18];
    const int* km1c_in  = (const int*)d_in[19];
    const int* km1c_out = (const int*)d_in[20];
    const int* km2_in   = (const int*)d_in[21];
    const int* km2_out  = (const int*)d_in[22];
    const int* km3a_in  = (const int*)d_in[23];
    const int* km3a_out = (const int*)d_in[24];
    const int* km3b_in  = (const int*)d_in[25];
    const int* km3b_out = (const int*)d_in[26];

    float* out  = (float*)d_out;
    float* x_e1 = out;                       // [N1,32]
    float* x_e2 = out + (size_t)N1c * 32;    // [N2,256]

    // ---- workspace layout (float-element offsets, 16B-aligned) ----
    float* ws = (float*)d_ws;
    float*  poolA  = ws;                        // 10,240,000 (h1 -> h3)
    float*  poolB  = poolA + 10240000;          //  5,120,000 (h2 -> h2b)
    double* dstats = (double*)(poolB + 5120000);//  2,048 doubles (4 layers x 512)
    float*  scsh   = (float*)(dstats + 2048);   //  1,024
    int*    bins   = (int*)(scsh + 1024);       //  819,200
    int*    ptr    = bins + 819200;             //  819,200
    int*    bsums  = ptr + 819200;              //  1,024
    int*    rank   = bsums + 1024;              //  2,500,000
    float*  contribf = (float*)(rank + 2500000);
    __half* contrib  = (__half*)contribf;
    const long long FIXED = 10240000LL + 5120000 + 4096 + 1024
                          + 819200 + 819200 + 1024 + 2500000;
    long long cap = (long long)(ws_size / 4) - FIXED - 32;   // fp32 elems left
    if (cap < 1) cap = 1;

    float* h1  = poolA;   // [N1,32]
    float* h3  = poolA;   // [N2,128] (h1 dead by then)
    float* h2  = poolB;   // [N1,32]
    float* h2b = poolB;   // [N2,64]  (h2 dead by then)

    double* dst1b = dstats;
    double* dst1c = dstats + 512;
    double* dst3a = dstats + 1024;
    double* dst3b = dstats + 1536;
    float* sc1b = scsh,       *sh1b = scsh + 32;
    float* sc3a = scsh + 256, *sh3a = scsh + 384;

    hipMemsetAsync(dstats, 0, 2048 * sizeof(double), stream);

    // ---- conv1a (1->32, K=125) + ReLU: scatter (val,k) + W-in-LDS reduce ----
    {
        build_csr2d(km1a_out, rank, bins, ptr, bsums, 125 * 20000, 20000, 125, 1,
                    STRIDE_N1, stream);
        hipLaunchKernelGGL(scatter_1a, dim3(2048), dim3(256), 0, stream,
                           x_feats, km1a_in, km1a_out, ptr, rank, (float2*)contribf,
                           125 * 20000, 20000);
        hipLaunchKernelGGL(phaseB_1a, dim3(2048), dim3(256), 0, stream,
                           (const float2*)contribf, ptr, w1a, h1, N1c);
    }

    // ---- conv1b (32->32, K=125): raw out + fp64 stats; BN fused at next gather
    run_layer<32, 32, 32, 8, 4, 0, true>(h1, w1b, km1b_in, km1b_out, h2, 20000, 125, N1c,
                                         STRIDE_N1, 8, bins, ptr, bsums, rank, contrib,
                                         cap, nullptr, nullptr, dst1b, stream);
    hipLaunchKernelGGL((make_scsh<32>), dim3(1), dim3(256), 0, stream,
                       dst1b, bn1b_g, bn1b_b, sc1b, sh1b, 1.0 / N1c);

    // ---- conv1c (32->32, K=125): BN(h2)+ReLU fused at gather; x_e1 raw + stats
    run_layer<32, 32, 32, 8, 4, 2, true>(h2, w1c, km1c_in, km1c_out, x_e1, 20000, 125, N1c,
                                         STRIDE_N1, 8, bins, ptr, bsums, rank, contrib,
                                         cap, sc1b, sh1b, dst1c, stream);
    hipLaunchKernelGGL((bn_apply_relu_kernel<32>), dim3(2048), dim3(256), 0, stream,
                       x_e1, N1c, dst1c, bn1c_g, bn1c_b);

    // ---- conv2 (32->64, K=27): plain, no activation ----
    run_layer<32, 32, 64, 8, 8, 0, false>(x_e1, w2, km2_in, km2_out, h2b, 30000, 27, N2c,
                                          STRIDE_N2, 10, bins, ptr, bsums, rank, contrib,
                                          cap, nullptr, nullptr, nullptr, stream);

    // ---- conv3a (64->128, K=27): raw out + stats; BN fused at conv3b gather
    run_layer<64, 32, 128, 8, 8, 0, true>(h2b, w3a, km3a_in, km3a_out, h3, 20000, 27, N2c,
                                          STRIDE_N2, 10, bins, ptr, bsums, rank, contrib,
                                          cap, nullptr, nullptr, dst3a, stream);
    hipLaunchKernelGGL((make_scsh<128>), dim3(1), dim3(256), 0, stream,
                       dst3a, bn3a_g, bn3a_b, sc3a, sh3a, 1.0 / N2c);

    // ---- conv3b (128->256, K=27): cout-split into two 128-halves ----
    // One CSR for the layer; per half: phaseA (BN(h3)+ReLU fused) + single phaseB.
    {
        const int M = 20000, K = 27;
        Plan pl = make_plan((long long)K * M * 128, K, cap * 2, 10);
        build_csr2d(km3b_out, rank, bins, ptr, bsums, K * M, M, pl.q, pl.nch,
                    STRIDE_N2, stream);
        constexpr int PP = (256 / (128 / 8)) * 8;   // 128 pairs per block
        for (int half = 0; half < 2; ++half) {
            for (int ch = 0; ch < pl.nch; ++ch) {
                int k0 = ch * pl.q;
                int qc = std::min(pl.q, K - k0);
                dim3 g((M + PP - 1) / PP, qc);
                hipLaunchKernelGGL((phaseA8<128, 32, 128, 256, 8, 8, 2>), g, dim3(256), 0, stream,
                                   h3, w3b + half * 128 + (size_t)k0 * 128 * 256,
                                   km3b_in + (size_t)k0 * M, km3b_out + (size_t)k0 * M,
                                   ptr + (size_t)ch * STRIDE_N2, rank + (size_t)k0 * M,
                                   contrib, M, sc3a, sh3a);
                bool last = (ch == pl.nch - 1);
                if (last)
                    hipLaunchKernelGGL((phaseB8<128, true>), dim3(2048), dim3(256), 0, stream,
                                       contrib, ptr + (size_t)ch * STRIDE_N2,
                                       x_e2 + half * 128, N2c, 256, ch ? 1 : 0,
                                       dst3b + half * 128, 256);
                else
                    hipLaunchKernelGGL((phaseB8<128, false>), dim3(2048), dim3(256), 0, stream,
                                       contrib, ptr + (size_t)ch * STRIDE_N2,
                                       x_e2 + half * 128, N2c, 256, ch ? 1 : 0,
                                       (double*)nullptr, 0);
            }
        }
        hipLaunchKernelGGL((bn_apply_relu_kernel<256>), dim3(2048), dim3(256), 0, stream,
                           x_e2, N2c, dst3b, bn3b_g, bn3b_b);
    }
}

// Round 5
// 2064.210 us; speedup vs baseline: 1.2000x; 1.0663x over previous
//
#include <hip/hip_runtime.h>
#include <hip/hip_fp16.h>
#include <cstdint>
#include <algorithm>

// ---------------- problem constants ----------------
#define N1c 100000
#define N2c 80000
#define EPSc 1e-5f
#define STRIDE_N1 102400   // 100 blocks of 1024 (>= N1+1 bins)
#define STRIDE_N2 81920    // 80 blocks of 1024  (>= N2+1 bins)

typedef _Float16 half2_t __attribute__((ext_vector_type(2)));

// fp32-accumulating dual-fp16 dot: d = a.x*b.x + a.y*b.y + c
__device__ __forceinline__ float dot2(half2_t a, half2_t b, float c)
{
#if __has_builtin(__builtin_amdgcn_fdot2)
    return __builtin_amdgcn_fdot2(a, b, c, false);
#else
    asm("v_dot2_f32_f16 %0, %1, %2, %0" : "+v"(c) : "v"(a), "v"(b));
    return c;
#endif
}

// ---------------- CSR build: one pass for ALL k-chunks of a layer ----------
__global__ __launch_bounds__(256) void rank2d_kernel(
    const int* __restrict__ out_idx, int* __restrict__ rank,
    int* __restrict__ bins, int E, int M, int q, int stride)
{
    for (int e = blockIdx.x * 256 + threadIdx.x; e < E; e += gridDim.x * 256) {
        int chunk = (e / M) / q;
        rank[e] = atomicAdd(&bins[chunk * stride + out_idx[e]], 1);
    }
}

__global__ __launch_bounds__(256) void scan1(
    const int* __restrict__ bins, int* __restrict__ ptr,
    int* __restrict__ bsums, int n)
{
    __shared__ int lds[256];
    int base = blockIdx.x * 1024;
    int v[4]; int t = 0;
    #pragma unroll
    for (int i = 0; i < 4; ++i) {
        int idx = base + threadIdx.x * 4 + i;
        v[i] = idx < n ? bins[idx] : 0;
        t += v[i];
    }
    lds[threadIdx.x] = t; __syncthreads();
    for (int off = 1; off < 256; off <<= 1) {
        int x = threadIdx.x >= off ? lds[threadIdx.x - off] : 0;
        __syncthreads();
        lds[threadIdx.x] += x;
        __syncthreads();
    }
    int run = lds[threadIdx.x] - t;
    if (threadIdx.x == 255) bsums[blockIdx.x] = lds[255];
    #pragma unroll
    for (int i = 0; i < 4; ++i) {
        int idx = base + threadIdx.x * 4 + i;
        if (idx < n) ptr[idx] = run;
        run += v[i];
    }
}

// serial exclusive scan of block sums, carry reset at chunk boundaries
__global__ __launch_bounds__(64) void scan2s(
    int* __restrict__ bsums, int bpc, int nch)
{
    int c = threadIdx.x;
    if (c < nch) {
        int run = 0;
        for (int i = 0; i < bpc; ++i) {
            int idx = c * bpc + i;
            int t = bsums[idx]; bsums[idx] = run; run += t;
        }
    }
}

__global__ __launch_bounds__(256) void scan3(
    int* __restrict__ ptr, const int* __restrict__ bsums, int n)
{
    int idx = blockIdx.x * 1024 + threadIdx.x * 4;
    int add = bsums[blockIdx.x];
    #pragma unroll
    for (int i = 0; i < 4; ++i)
        if (idx + i < n) ptr[idx + i] += add;
}

// ---------------- conv1a special: scatter (x_val, k) 8B per edge ----------
__global__ __launch_bounds__(256) void scatter_1a(
    const float* __restrict__ x, const int* __restrict__ iin,
    const int* __restrict__ iout, const int* __restrict__ ptr,
    const int* __restrict__ rank, float2* __restrict__ payload, int E, int M)
{
    for (int e = blockIdx.x * 256 + threadIdx.x; e < E; e += gridDim.x * 256) {
        int k = e / M;
        float2 p; p.x = x[iin[e]]; p.y = __int_as_float(k);
        payload[ptr[iout[e]] + rank[e]] = p;
    }
}

// out[o][c] = relu( sum_e val_e * W[k_e][c] ), W (125x32) in LDS
__global__ __launch_bounds__(256) void phaseB_1a(
    const float2* __restrict__ payload, const int* __restrict__ ptr,
    const float* __restrict__ W, float* __restrict__ out, int n)
{
    __shared__ float Wl[125 * 32];
    for (int i = threadIdx.x; i < 125 * 32; i += 256) Wl[i] = W[i];
    __syncthreads();
    int total = n * 32;
    for (int idx = blockIdx.x * 256 + threadIdx.x; idx < total; idx += gridDim.x * 256) {
        int o = idx >> 5, c = idx & 31;
        int s0 = ptr[o], s1 = ptr[o + 1];
        float acc = 0.f;
        for (int s = s0; s < s1; ++s) {
            float2 p = payload[s];
            acc = fmaf(p.x, Wl[(__float_as_int(p.y) << 5) + c], acc);
        }
        out[idx] = fmaxf(acc, 0.f);
    }
}

// ---------------- Phase A: tiled gather-GEMM, v_dot2_f32_f16 inner loop ----
// Thread tile = TP pairs x TC couts. GMODE: 0 plain, 2 BN+ReLU at gather.
// ft/Wl stored as packed half2 over adjacent cin channels: halves VALU issue
// (dot2 = 2 MACs/inst, fp32 accumulate), halves LDS bytes and footprint
// (conv3: 33.8->17KB -> 8 blocks/CU). Operand rounding to fp16 (11-bit
// mantissa) is below the fp16-contrib rounding already shown invisible.
// Wl column-group permutation (chunk (cg,g) at col (g*NCG+cg)*4) keeps wv
// reads conflict-free (verified r3: conflicts 1.74e7 -> 2.2e6).
// Contrib fp16 (verified r4: WRITE halved, absmax unchanged).
template <int CIN, int CINC, int CTILE, int WST, int TP, int TC, int GMODE>
__global__ __launch_bounds__(256) void phaseA8(
    const float* __restrict__ feats, const float* __restrict__ W,
    const int* __restrict__ in_idx, const int* __restrict__ out_idx,
    const int* __restrict__ ptr, const int* __restrict__ rank,
    __half* __restrict__ contrib, int M,
    const float* __restrict__ sc, const float* __restrict__ sh)
{
    constexpr int NCG = CTILE / TC;      // cout groups
    constexpr int PPG = 256 / NCG;       // pair groups
    constexpr int PP  = PPG * TP;        // pairs per block
    constexpr int NCH  = CIN / CINC;
    constexpr int LOADERS = 256 / PP;
    constexpr int SITER = CINC / 4 / LOADERS;
    constexpr int FTS = PP + 4;          // multiple of 4
    static_assert(SITER >= 1, "CINC too small for loader layout");
    static_assert((CINC % 2) == 0 && (TP % 4) == 0 && (TC % 4) == 0, "");

    const int k = blockIdx.y;
    __shared__ half2_t Wl[CINC / 2][CTILE];   // [cin-pair][cout] {row2j,row2j+1}
    __shared__ half2_t ft[CINC / 2][FTS];     // [cin-pair][pair]
    __shared__ int sslot[PP];

    const int cg = threadIdx.x % NCG;
    const int pg = threadIdx.x / NCG;
    const int p0 = pg * TP;
    const int pl = threadIdx.x % PP;
    const int ll = threadIdx.x / PP;

    const int* iin  = in_idx  + (size_t)k * M;
    const int* iout = out_idx + (size_t)k * M;
    const int* rk   = rank    + (size_t)k * M;
    const float* Wk = W + (size_t)k * CIN * WST;

    for (int base = blockIdx.x * PP; base < M; base += gridDim.x * PP) {
        float acc[TP][TC];
        #pragma unroll
        for (int p = 0; p < TP; ++p)
            #pragma unroll
            for (int c = 0; c < TC; ++c) acc[p][c] = 0.f;

        #pragma unroll
        for (int ch = 0; ch < NCH; ++ch) {
            __syncthreads();
            // stage W chunk: pack row-pairs into half2, column-group permuted
            for (int i = threadIdx.x; i < (CINC / 2) * (CTILE / 4); i += 256) {
                int j2 = i / (CTILE / 4), q = i % (CTILE / 4);
                int gq = q % (TC / 4);          // g of this 4-col chunk
                int cq = q / (TC / 4);          // cg of this chunk
                int pq = gq * NCG + cq;         // permuted chunk position
                const float* wr = Wk + (size_t)(ch * CINC + 2 * j2) * WST + q * 4;
                float4 a = *(const float4*)wr;
                float4 b = *(const float4*)(wr + WST);
                half2_t t[4];
                t[0][0] = (_Float16)a.x; t[0][1] = (_Float16)b.x;
                t[1][0] = (_Float16)a.y; t[1][1] = (_Float16)b.y;
                t[2][0] = (_Float16)a.z; t[2][1] = (_Float16)b.z;
                t[3][0] = (_Float16)a.w; t[3][1] = (_Float16)b.w;
                *(uint4*)&Wl[j2][pq * 4] = *(uint4*)t;
            }
            int p = base + pl;
            if (p < M) {
                if (ch == 0 && threadIdx.x < PP)
                    sslot[pl] = ptr[iout[p]] + rk[p];
                const float* fr = feats + (size_t)iin[p] * CIN + ch * CINC;
                #pragma unroll
                for (int i = 0; i < SITER; ++i) {
                    int j4 = (ll + i * LOADERS) * 4;
                    float4 v = *(const float4*)(fr + j4);
                    if (GMODE == 2) {
                        float4 s4 = *(const float4*)(sc + ch * CINC + j4);
                        float4 h4 = *(const float4*)(sh + ch * CINC + j4);
                        v.x = fmaxf(fmaf(v.x, s4.x, h4.x), 0.f);
                        v.y = fmaxf(fmaf(v.y, s4.y, h4.y), 0.f);
                        v.z = fmaxf(fmaf(v.z, s4.z, h4.z), 0.f);
                        v.w = fmaxf(fmaf(v.w, s4.w, h4.w), 0.f);
                    }
                    half2_t lo, hi;
                    lo[0] = (_Float16)v.x; lo[1] = (_Float16)v.y;
                    hi[0] = (_Float16)v.z; hi[1] = (_Float16)v.w;
                    ft[j4 / 2 + 0][pl] = lo;
                    ft[j4 / 2 + 1][pl] = hi;
                }
            }
            __syncthreads();

            #pragma unroll 4
            for (int j2 = 0; j2 < CINC / 2; ++j2) {
                half2_t fv[TP], wv[TC];
                #pragma unroll
                for (int g = 0; g < TP / 4; ++g)
                    *(uint4*)&fv[g * 4] = *(const uint4*)&ft[j2][p0 + g * 4];
                #pragma unroll
                for (int g = 0; g < TC / 4; ++g)
                    *(uint4*)&wv[g * 4] = *(const uint4*)&Wl[j2][(g * NCG + cg) * 4];
                #pragma unroll
                for (int pp = 0; pp < TP; ++pp)
                    #pragma unroll
                    for (int c = 0; c < TC; ++c)
                        acc[pp][c] = dot2(fv[pp], wv[c], acc[pp][c]);
            }
        }

        #pragma unroll
        for (int q = 0; q < TP; ++q) {
            if (base + p0 + q < M) {
                size_t s = (size_t)sslot[p0 + q];
                #pragma unroll
                for (int g = 0; g < TC / 4; ++g) {
                    __half2 h0 = __floats2half2_rn(acc[q][g * 4 + 0], acc[q][g * 4 + 1]);
                    __half2 h1 = __floats2half2_rn(acc[q][g * 4 + 2], acc[q][g * 4 + 3]);
                    uint2 pk;
                    pk.x = *(unsigned int*)&h0;
                    pk.y = *(unsigned int*)&h1;
                    *(uint2*)&contrib[s * CTILE + cg * TC + g * 4] = pk;
                }
            }
        }
    }
}

// ---------------- Phase B: segmented sum (+optional fused fp64 BN stats) ---
template <int CSTR, bool STATS>
__global__ __launch_bounds__(256) void phaseB8(
    const __half* __restrict__ contrib, const int* __restrict__ ptr,
    float* __restrict__ out, int n, int ostr, int accum,
    double* __restrict__ statsbuf, int sqoff)
{
    float s1 = 0.f, s2 = 0.f;
    int total = n * CSTR;
    for (int idx = blockIdx.x * 256 + threadIdx.x; idx < total; idx += gridDim.x * 256) {
        int o = idx / CSTR, c = idx % CSTR;
        int a = ptr[o], b = ptr[o + 1];
        float acc = accum ? out[(size_t)o * ostr + c] : 0.f;
        for (int s = a; s < b; ++s)
            acc += __half2float(contrib[(size_t)s * CSTR + c]);
        out[(size_t)o * ostr + c] = acc;
        if (STATS) { s1 += acc; s2 += acc * acc; }
    }
    if constexpr (STATS) {
        __shared__ double l1[256], l2[256];
        l1[threadIdx.x] = (double)s1; l2[threadIdx.x] = (double)s2;
        __syncthreads();
        for (int off = 128; off >= CSTR; off >>= 1) {
            if (threadIdx.x < (unsigned)off) {
                l1[threadIdx.x] += l1[threadIdx.x + off];
                l2[threadIdx.x] += l2[threadIdx.x + off];
            }
            __syncthreads();
        }
        if (threadIdx.x < CSTR) {
            atomicAdd(&statsbuf[threadIdx.x], l1[threadIdx.x]);
            atomicAdd(&statsbuf[sqoff + threadIdx.x], l2[threadIdx.x]);
        }
    }
}

// ---------------- BN helpers (fp64 stats) ----------------
template <int C>
__global__ __launch_bounds__(256) void make_scsh(
    const double* __restrict__ sums, const float* __restrict__ g,
    const float* __restrict__ b, float* __restrict__ sc, float* __restrict__ sh,
    double inv_n)
{
    int c = threadIdx.x;
    if (c < C) {
        double mean = sums[c] * inv_n;
        double var  = sums[C + c] * inv_n - mean * mean;
        float s = g[c] * (float)(1.0 / sqrt(var + (double)EPSc));
        sc[c] = s;
        sh[c] = b[c] - (float)mean * s;
    }
}

template <int C>
__global__ __launch_bounds__(256) void bn_apply_relu_kernel(
    float* __restrict__ x, int n, const double* __restrict__ sums,
    const float* __restrict__ g, const float* __restrict__ b)
{
    const int c = threadIdx.x % C;
    const double inv_n = 1.0 / (double)n;
    double mean = sums[c] * inv_n;
    double var  = sums[C + c] * inv_n - mean * mean;
    float scale = g[c] * (float)(1.0 / sqrt(var + (double)EPSc));
    float shift = b[c] - (float)mean * scale;
    size_t total = (size_t)n * C;
    size_t stride = (size_t)gridDim.x * 256;
    for (size_t i = (size_t)blockIdx.x * 256 + threadIdx.x; i < total; i += stride)
        x[i] = fmaxf(x[i] * scale + shift, 0.f);
}

// ---------------- host-side helpers ----------------
struct Plan { int q, nch; };

static Plan make_plan(long long tot_elems, int K, long long cap, int maxch)
{
    if (cap < 1) cap = 1;
    long long nch0 = (tot_elems + cap - 1) / cap;
    if (nch0 < 1) nch0 = 1;
    if (nch0 > K) nch0 = K;
    int q = (int)((K + nch0 - 1) / nch0);
    int nch = (K + q - 1) / q;
    if (nch > maxch) { q = (K + maxch - 1) / maxch; nch = (K + q - 1) / q; }
    return { q, nch };
}

static void build_csr2d(const int* iout, int* rank, int* bins, int* ptr, int* bsums,
                        int E, int M, int q, int nch, int stride, hipStream_t s)
{
    hipMemsetAsync(bins, 0, (size_t)nch * stride * sizeof(int), s);
    int gb = std::min(2048, (E + 255) / 256);
    hipLaunchKernelGGL(rank2d_kernel, dim3(gb), dim3(256), 0, s, iout, rank, bins, E, M, q, stride);
    int totalbins = nch * stride, nb = totalbins / 1024, bpc = stride / 1024;
    hipLaunchKernelGGL(scan1, dim3(nb), dim3(256), 0, s, bins, ptr, bsums, totalbins);
    hipLaunchKernelGGL(scan2s, dim3(1), dim3(64), 0, s, bsums, bpc, nch);
    hipLaunchKernelGGL(scan3, dim3(nb), dim3(256), 0, s, ptr, bsums, totalbins);
}

// One full layer (no cout split): k-chunked as needed.
template <int CIN, int CINC, int COUT, int TP, int TC, int GMODE, bool STATS>
static void run_layer(const float* feats, const float* W,
                      const int* iin, const int* iout, float* outp,
                      int M, int K, int n_out, int stride, int maxch,
                      int* bins, int* ptr, int* bsums, int* rank, __half* contrib,
                      long long cap_f32, const float* sc, const float* sh,
                      double* statsbuf, hipStream_t s)
{
    constexpr int NCG = COUT / TC;
    constexpr int PP  = (256 / NCG) * TP;
    long long cap_h = cap_f32 * 2;   // contrib region holds half-precision elems
    Plan pl = make_plan((long long)K * M * COUT, K, cap_h, maxch);
    build_csr2d(iout, rank, bins, ptr, bsums, K * M, M, pl.q, pl.nch, stride, s);
    for (int ch = 0; ch < pl.nch; ++ch) {
        int k0 = ch * pl.q;
        int qc = std::min(pl.q, K - k0);
        dim3 g((M + PP - 1) / PP, qc);
        hipLaunchKernelGGL((phaseA8<CIN, CINC, COUT, COUT, TP, TC, GMODE>), g, dim3(256), 0, s,
                           feats, W + (size_t)k0 * CIN * COUT,
                           iin + (size_t)k0 * M, iout + (size_t)k0 * M,
                           ptr + (size_t)ch * stride, rank + (size_t)k0 * M,
                           contrib, M, sc, sh);
        bool last = (ch == pl.nch - 1);
        if (STATS && last)
            hipLaunchKernelGGL((phaseB8<COUT, true>), dim3(2048), dim3(256), 0, s,
                               contrib, ptr + (size_t)ch * stride, outp, n_out, COUT,
                               ch ? 1 : 0, statsbuf, COUT);
        else
            hipLaunchKernelGGL((phaseB8<COUT, false>), dim3(2048), dim3(256), 0, s,
                               contrib, ptr + (size_t)ch * stride, outp, n_out, COUT,
                               ch ? 1 : 0, (double*)nullptr, 0);
    }
}

extern "C" void kernel_launch(void* const* d_in, const int* in_sizes, int n_in,
                              void* d_out, int out_size, void* d_ws, size_t ws_size,
                              hipStream_t stream)
{
    const float* x_feats = (const float*)d_in[0];
    const float* w1a = (const float*)d_in[1];
    const float* w1b = (const float*)d_in[2];
    const float* w1c = (const float*)d_in[3];
    const float* w2  = (const float*)d_in[4];
    const float* w3a = (const float*)d_in[5];
    const float* w3b = (const float*)d_in[6];
    const float* bn1b_g = (const float*)d_in[7];
    const float* bn1b_b = (const float*)d_in[8];
    const float* bn1c_g = (const float*)d_in[9];
    const float* bn1c_b = (const float*)d_in[10];
    const float* bn3a_g = (const float*)d_in[11];
    const float* bn3a_b = (const float*)d_in[12];
    const float* bn3b_g = (const float*)d_in[13];
    const float* bn3b_b = (const float*)d_in[14];
    const int* km1a_in  = (const int*)d_in[15];
    const int* km1a_out = (const int*)d_in[16];
    const int* km1b_in  = (const int*)d_in[17];
    const int* km1b_out = (const int*)d_in[18];
    const int* km1c_in  = (const int*)d_in[19];
    const int* km1c_out = (const int*)d_in[20];
    const int* km2_in   = (const int*)d_in[21];
    const int* km2_out  = (const int*)d_in[22];
    const int* km3a_in  = (const int*)d_in[23];
    const int* km3a_out = (const int*)d_in[24];
    const int* km3b_in  = (const int*)d_in[25];
    const int* km3b_out = (const int*)d_in[26];

    float* out  = (float*)d_out;
    float* x_e1 = out;                       // [N1,32]
    float* x_e2 = out + (size_t)N1c * 32;    // [N2,256]

    // ---- workspace layout (float-element offsets, 16B-aligned) ----
    float* ws = (float*)d_ws;
    float*  poolA  = ws;                        // 10,240,000 (h1 -> h3)
    float*  poolB  = poolA + 10240000;          //  5,120,000 (h2 -> h2b)
    double* dstats = (double*)(poolB + 5120000);//  2,048 doubles (4 layers x 512)
    float*  scsh   = (float*)(dstats + 2048);   //  1,024
    int*    bins   = (int*)(scsh + 1024);       //  819,200
    int*    ptr    = bins + 819200;             //  819,200
    int*    bsums  = ptr + 819200;              //  1,024
    int*    rank   = bsums + 1024;              //  2,500,000
    float*  contribf = (float*)(rank + 2500000);
    __half* contrib  = (__half*)contribf;
    const long long FIXED = 10240000LL + 5120000 + 4096 + 1024
                          + 819200 + 819200 + 1024 + 2500000;
    long long cap = (long long)(ws_size / 4) - FIXED - 32;   // fp32 elems left
    if (cap < 1) cap = 1;

    float* h1  = poolA;   // [N1,32]
    float* h3  = poolA;   // [N2,128] (h1 dead by then)
    float* h2  = poolB;   // [N1,32]
    float* h2b = poolB;   // [N2,64]  (h2 dead by then)

    double* dst1b = dstats;
    double* dst1c = dstats + 512;
    double* dst3a = dstats + 1024;
    double* dst3b = dstats + 1536;
    float* sc1b = scsh,       *sh1b = scsh + 32;
    float* sc3a = scsh + 256, *sh3a = scsh + 384;

    hipMemsetAsync(dstats, 0, 2048 * sizeof(double), stream);

    // ---- conv1a (1->32, K=125) + ReLU: scatter (val,k) + W-in-LDS reduce ----
    {
        build_csr2d(km1a_out, rank, bins, ptr, bsums, 125 * 20000, 20000, 125, 1,
                    STRIDE_N1, stream);
        hipLaunchKernelGGL(scatter_1a, dim3(2048), dim3(256), 0, stream,
                           x_feats, km1a_in, km1a_out, ptr, rank, (float2*)contribf,
                           125 * 20000, 20000);
        hipLaunchKernelGGL(phaseB_1a, dim3(2048), dim3(256), 0, stream,
                           (const float2*)contribf, ptr, w1a, h1, N1c);
    }

    // ---- conv1b (32->32, K=125): raw out + fp64 stats; BN fused at next gather
    run_layer<32, 32, 32, 8, 4, 0, true>(h1, w1b, km1b_in, km1b_out, h2, 20000, 125, N1c,
                                         STRIDE_N1, 8, bins, ptr, bsums, rank, contrib,
                                         cap, nullptr, nullptr, dst1b, stream);
    hipLaunchKernelGGL((make_scsh<32>), dim3(1), dim3(256), 0, stream,
                       dst1b, bn1b_g, bn1b_b, sc1b, sh1b, 1.0 / N1c);

    // ---- conv1c (32->32, K=125): BN(h2)+ReLU fused at gather; x_e1 raw + stats
    run_layer<32, 32, 32, 8, 4, 2, true>(h2, w1c, km1c_in, km1c_out, x_e1, 20000, 125, N1c,
                                         STRIDE_N1, 8, bins, ptr, bsums, rank, contrib,
                                         cap, sc1b, sh1b, dst1c, stream);
    hipLaunchKernelGGL((bn_apply_relu_kernel<32>), dim3(2048), dim3(256), 0, stream,
                       x_e1, N1c, dst1c, bn1c_g, bn1c_b);

    // ---- conv2 (32->64, K=27): plain, no activation ----
    run_layer<32, 32, 64, 8, 8, 0, false>(x_e1, w2, km2_in, km2_out, h2b, 30000, 27, N2c,
                                          STRIDE_N2, 10, bins, ptr, bsums, rank, contrib,
                                          cap, nullptr, nullptr, nullptr, stream);

    // ---- conv3a (64->128, K=27): raw out + stats; BN fused at conv3b gather
    run_layer<64, 32, 128, 8, 8, 0, true>(h2b, w3a, km3a_in, km3a_out, h3, 20000, 27, N2c,
                                          STRIDE_N2, 10, bins, ptr, bsums, rank, contrib,
                                          cap, nullptr, nullptr, dst3a, stream);
    hipLaunchKernelGGL((make_scsh<128>), dim3(1), dim3(256), 0, stream,
                       dst3a, bn3a_g, bn3a_b, sc3a, sh3a, 1.0 / N2c);

    // ---- conv3b (128->256, K=27): cout-split into two 128-halves ----
    // One CSR for the layer; per half: phaseA (BN(h3)+ReLU fused) + single phaseB.
    {
        const int M = 20000, K = 27;
        Plan pl = make_plan((long long)K * M * 128, K, cap * 2, 10);
        build_csr2d(km3b_out, rank, bins, ptr, bsums, K * M, M, pl.q, pl.nch,
                    STRIDE_N2, stream);
        constexpr int PP = (256 / (128 / 8)) * 8;   // 128 pairs per block
        for (int half = 0; half < 2; ++half) {
            for (int ch = 0; ch < pl.nch; ++ch) {
                int k0 = ch * pl.q;
                int qc = std::min(pl.q, K - k0);
                dim3 g((M + PP - 1) / PP, qc);
                hipLaunchKernelGGL((phaseA8<128, 32, 128, 256, 8, 8, 2>), g, dim3(256), 0, stream,
                                   h3, w3b + half * 128 + (size_t)k0 * 128 * 256,
                                   km3b_in + (size_t)k0 * M, km3b_out + (size_t)k0 * M,
                                   ptr + (size_t)ch * STRIDE_N2, rank + (size_t)k0 * M,
                                   contrib, M, sc3a, sh3a);
                bool last = (ch == pl.nch - 1);
                if (last)
                    hipLaunchKernelGGL((phaseB8<128, true>), dim3(2048), dim3(256), 0, stream,
                                       contrib, ptr + (size_t)ch * STRIDE_N2,
                                       x_e2 + half * 128, N2c, 256, ch ? 1 : 0,
                                       dst3b + half * 128, 256);
                else
                    hipLaunchKernelGGL((phaseB8<128, false>), dim3(2048), dim3(256), 0, stream,
                                       contrib, ptr + (size_t)ch * STRIDE_N2,
                                       x_e2 + half * 128, N2c, 256, ch ? 1 : 0,
                                       (double*)nullptr, 0);
            }
        }
        hipLaunchKernelGGL((bn_apply_relu_kernel<256>), dim3(2048), dim3(256), 0, stream,
                           x_e2, N2c, dst3b, bn3b_g, bn3b_b);
    }
}

// Round 6
// 1989.224 us; speedup vs baseline: 1.2452x; 1.0377x over previous
//
#include <hip/hip_runtime.h>
#include <hip/hip_fp16.h>
#include <cstdint>
#include <algorithm>

// ---------------- problem constants ----------------
#define N1c 100000
#define N2c 80000
#define EPSc 1e-5f
#define STRIDE_N1 102400   // 100 blocks of 1024 (>= N1+1 bins)
#define STRIDE_N2 81920    // 80 blocks of 1024  (>= N2+1 bins)

typedef _Float16 fp16x8 __attribute__((ext_vector_type(8)));
typedef float f32x4 __attribute__((ext_vector_type(4)));

// ---------------- CSR build: one pass for ALL k-chunks of a layer ----------
__global__ __launch_bounds__(256) void rank2d_kernel(
    const int* __restrict__ out_idx, int* __restrict__ rank,
    int* __restrict__ bins, int E, int M, int q, int stride)
{
    for (int e = blockIdx.x * 256 + threadIdx.x; e < E; e += gridDim.x * 256) {
        int chunk = (e / M) / q;
        rank[e] = atomicAdd(&bins[chunk * stride + out_idx[e]], 1);
    }
}

__global__ __launch_bounds__(256) void scan1(
    const int* __restrict__ bins, int* __restrict__ ptr,
    int* __restrict__ bsums, int n)
{
    __shared__ int lds[256];
    int base = blockIdx.x * 1024;
    int v[4]; int t = 0;
    #pragma unroll
    for (int i = 0; i < 4; ++i) {
        int idx = base + threadIdx.x * 4 + i;
        v[i] = idx < n ? bins[idx] : 0;
        t += v[i];
    }
    lds[threadIdx.x] = t; __syncthreads();
    for (int off = 1; off < 256; off <<= 1) {
        int x = threadIdx.x >= off ? lds[threadIdx.x - off] : 0;
        __syncthreads();
        lds[threadIdx.x] += x;
        __syncthreads();
    }
    int run = lds[threadIdx.x] - t;
    if (threadIdx.x == 255) bsums[blockIdx.x] = lds[255];
    #pragma unroll
    for (int i = 0; i < 4; ++i) {
        int idx = base + threadIdx.x * 4 + i;
        if (idx < n) ptr[idx] = run;
        run += v[i];
    }
}

// serial exclusive scan of block sums, carry reset at chunk boundaries
__global__ __launch_bounds__(64) void scan2s(
    int* __restrict__ bsums, int bpc, int nch)
{
    int c = threadIdx.x;
    if (c < nch) {
        int run = 0;
        for (int i = 0; i < bpc; ++i) {
            int idx = c * bpc + i;
            int t = bsums[idx]; bsums[idx] = run; run += t;
        }
    }
}

__global__ __launch_bounds__(256) void scan3(
    int* __restrict__ ptr, const int* __restrict__ bsums, int n)
{
    int idx = blockIdx.x * 1024 + threadIdx.x * 4;
    int add = bsums[blockIdx.x];
    #pragma unroll
    for (int i = 0; i < 4; ++i)
        if (idx + i < n) ptr[idx + i] += add;
}

// ---------------- conv1a special: scatter (x_val, k) 8B per edge ----------
__global__ __launch_bounds__(256) void scatter_1a(
    const float* __restrict__ x, const int* __restrict__ iin,
    const int* __restrict__ iout, const int* __restrict__ ptr,
    const int* __restrict__ rank, float2* __restrict__ payload, int E, int M)
{
    for (int e = blockIdx.x * 256 + threadIdx.x; e < E; e += gridDim.x * 256) {
        int k = e / M;
        float2 p; p.x = x[iin[e]]; p.y = __int_as_float(k);
        payload[ptr[iout[e]] + rank[e]] = p;
    }
}

// out[o][c] = relu( sum_e val_e * W[k_e][c] ), W (125x32) in LDS
__global__ __launch_bounds__(256) void phaseB_1a(
    const float2* __restrict__ payload, const int* __restrict__ ptr,
    const float* __restrict__ W, float* __restrict__ out, int n)
{
    __shared__ float Wl[125 * 32];
    for (int i = threadIdx.x; i < 125 * 32; i += 256) Wl[i] = W[i];
    __syncthreads();
    int total = n * 32;
    for (int idx = blockIdx.x * 256 + threadIdx.x; idx < total; idx += gridDim.x * 256) {
        int o = idx >> 5, c = idx & 31;
        int s0 = ptr[o], s1 = ptr[o + 1];
        float acc = 0.f;
        for (int s = s0; s < s1; ++s) {
            float2 p = payload[s];
            acc = fmaf(p.x, Wl[(__float_as_int(p.y) << 5) + c], acc);
        }
        out[idx] = fmaxf(acc, 0.f);
    }
}

// ---------------- Phase A: MFMA gather-GEMM ----------------
// Per (tile,k) block: C[128 pairs][CTILE couts] = G[128][CIN] x W_k[CIN][CTILE]
// via v_mfma_f32_16x16x32_f16 (fp16 operands, fp32 accumulate — numerically
// identical to the round-5 dot2 path; VALU dot2 measured at ~fp32-fma FLOP
// rate, so matrix pipe is the only way below the ~115us/half VALU floor).
// Layouts (m89-verified convention):
//   A frag: lane reads SRC[row = lane&15][k = 8*(lane>>4) + 0..7]
//   B frag: lane reads SRC^T stored [cout][cin], same pattern
//   C/D:    col = lane&15, row = 4*(lane>>4) + reg
// Both LDS operands stored [16-row tiles][CIN] fp16 with XOR chunk swizzle
// (chunk ^= row & GSM) so the 16-lane row-stride read is bank-spread.
// GMODE: 0 plain gather, 2 BN(scale/shift)+ReLU at gather. Contrib fp16
// (r4-verified). Output rows scattered per-pair via sslot.
template <int CIN, int CTILE, int WST, int GMODE>
__global__ __launch_bounds__(256) void phaseA_mfma(
    const float* __restrict__ feats, const float* __restrict__ W,
    const int* __restrict__ in_idx, const int* __restrict__ out_idx,
    const int* __restrict__ ptr, const int* __restrict__ rank,
    __half* __restrict__ contrib, int M,
    const float* __restrict__ sc, const float* __restrict__ sh)
{
    constexpr int PP  = 128;             // pairs per block
    constexpr int NK  = CIN / 32;        // K-steps
    constexpr int NCF = CTILE / 16;      // col fragments
    constexpr int NRF = 2;               // row fragments per wave (32 pairs)
    constexpr int GCHK = (CIN * 2) / 16; // 16B chunks per row
    constexpr int GSM  = (GCHK < 8 ? GCHK : 8) - 1;
    static_assert(CIN % 32 == 0 && CTILE % 16 == 0, "");

    __shared__ __align__(16) _Float16 Gl[PP * CIN];     // [pair][cin]
    __shared__ __align__(16) _Float16 Wt[CTILE * CIN];  // [cout][cin] = W^T
    __shared__ int sslot[PP];

    const int tid  = threadIdx.x;
    const int wave = tid >> 6;
    const int lane = tid & 63;
    const int k    = blockIdx.y;

    const int* iin  = in_idx  + (size_t)k * M;
    const int* iout = out_idx + (size_t)k * M;
    const int* rk   = rank    + (size_t)k * M;
    const float* Wk = W + (size_t)k * CIN * WST;

    for (int base = blockIdx.x * PP; base < M; base += gridDim.x * PP) {
        // ---- sslot ----
        if (tid < PP && base + tid < M)
            sslot[tid] = ptr[iout[base + tid]] + rk[base + tid];

        // ---- stage G: 2 threads per pair-row, fp32->fp16, swizzled ----
        {
            int r  = tid & (PP - 1);
            int hh = tid >> 7;               // which half of the row
            int p  = base + r;
            if (p < M) {
                const int c0 = hh * (CIN / 2);
                const float* fr = feats + (size_t)iin[p] * CIN + c0;
                #pragma unroll
                for (int c = 0; c < CIN / 2; c += 8) {
                    float a[8];
                    *(float4*)&a[0] = *(const float4*)(fr + c);
                    *(float4*)&a[4] = *(const float4*)(fr + c + 4);
                    if (GMODE == 2) {
                        float s[8], h[8];
                        *(float4*)&s[0] = *(const float4*)(sc + c0 + c);
                        *(float4*)&s[4] = *(const float4*)(sc + c0 + c + 4);
                        *(float4*)&h[0] = *(const float4*)(sh + c0 + c);
                        *(float4*)&h[4] = *(const float4*)(sh + c0 + c + 4);
                        #pragma unroll
                        for (int j = 0; j < 8; ++j)
                            a[j] = fmaxf(fmaf(a[j], s[j], h[j]), 0.f);
                    }
                    _Float16 t[8];
                    #pragma unroll
                    for (int j = 0; j < 8; ++j) t[j] = (_Float16)a[j];
                    int col = c0 + c;
                    int idx = r * CIN + ((((col >> 3) ^ (r & GSM))) << 3);
                    *(uint4*)&Gl[idx] = *(uint4*)t;
                }
            }
        }

        // ---- stage W^T: 4 couts x 4 kins per iter, swizzled b64 writes ----
        for (int i = tid; i < (CTILE / 4) * (CIN / 4); i += 256) {
            int c4 = (i % (CTILE / 4)) * 4;
            int k4 = (i / (CTILE / 4)) * 4;
            const float* wr = Wk + (size_t)k4 * WST + c4;
            float a0[4], a1[4], a2[4], a3[4];
            *(float4*)a0 = *(const float4*)wr;
            *(float4*)a1 = *(const float4*)(wr + WST);
            *(float4*)a2 = *(const float4*)(wr + 2 * (size_t)WST);
            *(float4*)a3 = *(const float4*)(wr + 3 * (size_t)WST);
            #pragma unroll
            for (int j = 0; j < 4; ++j) {
                _Float16 t[4] = { (_Float16)a0[j], (_Float16)a1[j],
                                  (_Float16)a2[j], (_Float16)a3[j] };
                int row = c4 + j;
                int idx = row * CIN + (((k4 >> 3) ^ (row & GSM)) << 3) + (k4 & 7);
                *(uint2*)&Wt[idx] = *(uint2*)t;
            }
        }
        __syncthreads();

        // ---- MFMA ----
        f32x4 acc[NRF][NCF];
        #pragma unroll
        for (int rf = 0; rf < NRF; ++rf)
            #pragma unroll
            for (int cf = 0; cf < NCF; ++cf)
                acc[rf][cf] = (f32x4){0.f, 0.f, 0.f, 0.f};

        const int lrow = lane & 15;
        const int lk8  = (lane >> 4) * 8;
        const int p0   = wave * 32;
        #pragma unroll
        for (int kk = 0; kk < NK; ++kk) {
            int col = kk * 32 + lk8;
            fp16x8 afr[NRF];
            #pragma unroll
            for (int rf = 0; rf < NRF; ++rf) {
                int r = p0 + rf * 16 + lrow;
                afr[rf] = *(const fp16x8*)
                    &Gl[r * CIN + (((col >> 3) ^ (r & GSM)) << 3)];
            }
            #pragma unroll
            for (int cf = 0; cf < NCF; ++cf) {
                int r = cf * 16 + lrow;
                fp16x8 bfr = *(const fp16x8*)
                    &Wt[r * CIN + (((col >> 3) ^ (r & GSM)) << 3)];
                #pragma unroll
                for (int rf = 0; rf < NRF; ++rf)
                    acc[rf][cf] = __builtin_amdgcn_mfma_f32_16x16x32_f16(
                        afr[rf], bfr, acc[rf][cf], 0, 0, 0);
            }
        }

        // ---- epilogue: scatter rows via sslot, fp32->fp16 ----
        #pragma unroll
        for (int rf = 0; rf < NRF; ++rf) {
            int prb = p0 + rf * 16 + (lane >> 4) * 4;
            #pragma unroll
            for (int b = 0; b < 4; ++b) {
                int pr = prb + b;
                if (base + pr < M) {
                    size_t s = (size_t)sslot[pr];
                    #pragma unroll
                    for (int cf = 0; cf < NCF; ++cf)
                        contrib[s * CTILE + cf * 16 + lrow] =
                            __float2half(acc[rf][cf][b]);
                }
            }
        }
        __syncthreads();
    }
}

// ---------------- Phase B: segmented sum (+optional fused fp64 BN stats) ---
template <int CSTR, bool STATS>
__global__ __launch_bounds__(256) void phaseB8(
    const __half* __restrict__ contrib, const int* __restrict__ ptr,
    float* __restrict__ out, int n, int ostr, int accum,
    double* __restrict__ statsbuf, int sqoff)
{
    float s1 = 0.f, s2 = 0.f;
    int total = n * CSTR;
    for (int idx = blockIdx.x * 256 + threadIdx.x; idx < total; idx += gridDim.x * 256) {
        int o = idx / CSTR, c = idx % CSTR;
        int a = ptr[o], b = ptr[o + 1];
        float acc = accum ? out[(size_t)o * ostr + c] : 0.f;
        for (int s = a; s < b; ++s)
            acc += __half2float(contrib[(size_t)s * CSTR + c]);
        out[(size_t)o * ostr + c] = acc;
        if (STATS) { s1 += acc; s2 += acc * acc; }
    }
    if constexpr (STATS) {
        __shared__ double l1[256], l2[256];
        l1[threadIdx.x] = (double)s1; l2[threadIdx.x] = (double)s2;
        __syncthreads();
        for (int off = 128; off >= CSTR; off >>= 1) {
            if (threadIdx.x < (unsigned)off) {
                l1[threadIdx.x] += l1[threadIdx.x + off];
                l2[threadIdx.x] += l2[threadIdx.x + off];
            }
            __syncthreads();
        }
        if (threadIdx.x < CSTR) {
            atomicAdd(&statsbuf[threadIdx.x], l1[threadIdx.x]);
            atomicAdd(&statsbuf[sqoff + threadIdx.x], l2[threadIdx.x]);
        }
    }
}

// ---------------- BN helpers (fp64 stats) ----------------
template <int C>
__global__ __launch_bounds__(256) void make_scsh(
    const double* __restrict__ sums, const float* __restrict__ g,
    const float* __restrict__ b, float* __restrict__ sc, float* __restrict__ sh,
    double inv_n)
{
    int c = threadIdx.x;
    if (c < C) {
        double mean = sums[c] * inv_n;
        double var  = sums[C + c] * inv_n - mean * mean;
        float s = g[c] * (float)(1.0 / sqrt(var + (double)EPSc));
        sc[c] = s;
        sh[c] = b[c] - (float)mean * s;
    }
}

template <int C>
__global__ __launch_bounds__(256) void bn_apply_relu_kernel(
    float* __restrict__ x, int n, const double* __restrict__ sums,
    const float* __restrict__ g, const float* __restrict__ b)
{
    const int c = threadIdx.x % C;
    const double inv_n = 1.0 / (double)n;
    double mean = sums[c] * inv_n;
    double var  = sums[C + c] * inv_n - mean * mean;
    float scale = g[c] * (float)(1.0 / sqrt(var + (double)EPSc));
    float shift = b[c] - (float)mean * scale;
    size_t total = (size_t)n * C;
    size_t stride = (size_t)gridDim.x * 256;
    for (size_t i = (size_t)blockIdx.x * 256 + threadIdx.x; i < total; i += stride)
        x[i] = fmaxf(x[i] * scale + shift, 0.f);
}

// ---------------- host-side helpers ----------------
struct Plan { int q, nch; };

static Plan make_plan(long long tot_elems, int K, long long cap, int maxch)
{
    if (cap < 1) cap = 1;
    long long nch0 = (tot_elems + cap - 1) / cap;
    if (nch0 < 1) nch0 = 1;
    if (nch0 > K) nch0 = K;
    int q = (int)((K + nch0 - 1) / nch0);
    int nch = (K + q - 1) / q;
    if (nch > maxch) { q = (K + maxch - 1) / maxch; nch = (K + q - 1) / q; }
    return { q, nch };
}

static void build_csr2d(const int* iout, int* rank, int* bins, int* ptr, int* bsums,
                        int E, int M, int q, int nch, int stride, hipStream_t s)
{
    hipMemsetAsync(bins, 0, (size_t)nch * stride * sizeof(int), s);
    int gb = std::min(2048, (E + 255) / 256);
    hipLaunchKernelGGL(rank2d_kernel, dim3(gb), dim3(256), 0, s, iout, rank, bins, E, M, q, stride);
    int totalbins = nch * stride, nb = totalbins / 1024, bpc = stride / 1024;
    hipLaunchKernelGGL(scan1, dim3(nb), dim3(256), 0, s, bins, ptr, bsums, totalbins);
    hipLaunchKernelGGL(scan2s, dim3(1), dim3(64), 0, s, bsums, bpc, nch);
    hipLaunchKernelGGL(scan3, dim3(nb), dim3(256), 0, s, ptr, bsums, totalbins);
}

// One full layer (no cout split): k-chunked as needed.
template <int CIN, int COUT, int GMODE, bool STATS>
static void run_layer(const float* feats, const float* W,
                      const int* iin, const int* iout, float* outp,
                      int M, int K, int n_out, int stride, int maxch,
                      int* bins, int* ptr, int* bsums, int* rank, __half* contrib,
                      long long cap_f32, const float* sc, const float* sh,
                      double* statsbuf, hipStream_t s)
{
    long long cap_h = cap_f32 * 2;   // contrib region holds half-precision elems
    Plan pl = make_plan((long long)K * M * COUT, K, cap_h, maxch);
    build_csr2d(iout, rank, bins, ptr, bsums, K * M, M, pl.q, pl.nch, stride, s);
    for (int ch = 0; ch < pl.nch; ++ch) {
        int k0 = ch * pl.q;
        int qc = std::min(pl.q, K - k0);
        dim3 g((M + 127) / 128, qc);
        hipLaunchKernelGGL((phaseA_mfma<CIN, COUT, COUT, GMODE>), g, dim3(256), 0, s,
                           feats, W + (size_t)k0 * CIN * COUT,
                           iin + (size_t)k0 * M, iout + (size_t)k0 * M,
                           ptr + (size_t)ch * stride, rank + (size_t)k0 * M,
                           contrib, M, sc, sh);
        bool last = (ch == pl.nch - 1);
        if (STATS && last)
            hipLaunchKernelGGL((phaseB8<COUT, true>), dim3(2048), dim3(256), 0, s,
                               contrib, ptr + (size_t)ch * stride, outp, n_out, COUT,
                               ch ? 1 : 0, statsbuf, COUT);
        else
            hipLaunchKernelGGL((phaseB8<COUT, false>), dim3(2048), dim3(256), 0, s,
                               contrib, ptr + (size_t)ch * stride, outp, n_out, COUT,
                               ch ? 1 : 0, (double*)nullptr, 0);
    }
}

extern "C" void kernel_launch(void* const* d_in, const int* in_sizes, int n_in,
                              void* d_out, int out_size, void* d_ws, size_t ws_size,
                              hipStream_t stream)
{
    const float* x_feats = (const float*)d_in[0];
    const float* w1a = (const float*)d_in[1];
    const float* w1b = (const float*)d_in[2];
    const float* w1c = (const float*)d_in[3];
    const float* w2  = (const float*)d_in[4];
    const float* w3a = (const float*)d_in[5];
    const float* w3b = (const float*)d_in[6];
    const float* bn1b_g = (const float*)d_in[7];
    const float* bn1b_b = (const float*)d_in[8];
    const float* bn1c_g = (const float*)d_in[9];
    const float* bn1c_b = (const float*)d_in[10];
    const float* bn3a_g = (const float*)d_in[11];
    const float* bn3a_b = (const float*)d_in[12];
    const float* bn3b_g = (const float*)d_in[13];
    const float* bn3b_b = (const float*)d_in[14];
    const int* km1a_in  = (const int*)d_in[15];
    const int* km1a_out = (const int*)d_in[16];
    const int* km1b_in  = (const int*)d_in[17];
    const int* km1b_out = (const int*)d_in[18];
    const int* km1c_in  = (const int*)d_in[19];
    const int* km1c_out = (const int*)d_in[20];
    const int* km2_in   = (const int*)d_in[21];
    const int* km2_out  = (const int*)d_in[22];
    const int* km3a_in  = (const int*)d_in[23];
    const int* km3a_out = (const int*)d_in[24];
    const int* km3b_in  = (const int*)d_in[25];
    const int* km3b_out = (const int*)d_in[26];

    float* out  = (float*)d_out;
    float* x_e1 = out;                       // [N1,32]
    float* x_e2 = out + (size_t)N1c * 32;    // [N2,256]

    // ---- workspace layout (float-element offsets, 16B-aligned) ----
    float* ws = (float*)d_ws;
    float*  poolA  = ws;                        // 10,240,000 (h1 -> h3)
    float*  poolB  = poolA + 10240000;          //  5,120,000 (h2 -> h2b)
    double* dstats = (double*)(poolB + 5120000);//  2,048 doubles (4 layers x 512)
    float*  scsh   = (float*)(dstats + 2048);   //  1,024
    int*    bins   = (int*)(scsh + 1024);       //  819,200
    int*    ptr    = bins + 819200;             //  819,200
    int*    bsums  = ptr + 819200;              //  1,024
    int*    rank   = bsums + 1024;              //  2,500,000
    float*  contribf = (float*)(rank + 2500000);
    __half* contrib  = (__half*)contribf;
    const long long FIXED = 10240000LL + 5120000 + 4096 + 1024
                          + 819200 + 819200 + 1024 + 2500000;
    long long cap = (long long)(ws_size / 4) - FIXED - 32;   // fp32 elems left
    if (cap < 1) cap = 1;

    float* h1  = poolA;   // [N1,32]
    float* h3  = poolA;   // [N2,128] (h1 dead by then)
    float* h2  = poolB;   // [N1,32]
    float* h2b = poolB;   // [N2,64]  (h2 dead by then)

    double* dst1b = dstats;
    double* dst1c = dstats + 512;
    double* dst3a = dstats + 1024;
    double* dst3b = dstats + 1536;
    float* sc1b = scsh,       *sh1b = scsh + 32;
    float* sc3a = scsh + 256, *sh3a = scsh + 384;

    hipMemsetAsync(dstats, 0, 2048 * sizeof(double), stream);

    // ---- conv1a (1->32, K=125) + ReLU: scatter (val,k) + W-in-LDS reduce ----
    {
        build_csr2d(km1a_out, rank, bins, ptr, bsums, 125 * 20000, 20000, 125, 1,
                    STRIDE_N1, stream);
        hipLaunchKernelGGL(scatter_1a, dim3(2048), dim3(256), 0, stream,
                           x_feats, km1a_in, km1a_out, ptr, rank, (float2*)contribf,
                           125 * 20000, 20000);
        hipLaunchKernelGGL(phaseB_1a, dim3(2048), dim3(256), 0, stream,
                           (const float2*)contribf, ptr, w1a, h1, N1c);
    }

    // ---- conv1b (32->32, K=125): raw out + fp64 stats; BN fused at next gather
    run_layer<32, 32, 0, true>(h1, w1b, km1b_in, km1b_out, h2, 20000, 125, N1c,
                               STRIDE_N1, 8, bins, ptr, bsums, rank, contrib,
                               cap, nullptr, nullptr, dst1b, stream);
    hipLaunchKernelGGL((make_scsh<32>), dim3(1), dim3(256), 0, stream,
                       dst1b, bn1b_g, bn1b_b, sc1b, sh1b, 1.0 / N1c);

    // ---- conv1c (32->32, K=125): BN(h2)+ReLU fused at gather; x_e1 raw + stats
    run_layer<32, 32, 2, true>(h2, w1c, km1c_in, km1c_out, x_e1, 20000, 125, N1c,
                               STRIDE_N1, 8, bins, ptr, bsums, rank, contrib,
                               cap, sc1b, sh1b, dst1c, stream);
    hipLaunchKernelGGL((bn_apply_relu_kernel<32>), dim3(2048), dim3(256), 0, stream,
                       x_e1, N1c, dst1c, bn1c_g, bn1c_b);

    // ---- conv2 (32->64, K=27): plain, no activation ----
    run_layer<32, 64, 0, false>(x_e1, w2, km2_in, km2_out, h2b, 30000, 27, N2c,
                                STRIDE_N2, 10, bins, ptr, bsums, rank, contrib,
                                cap, nullptr, nullptr, nullptr, stream);

    // ---- conv3a (64->128, K=27): raw out + stats; BN fused at conv3b gather
    run_layer<64, 128, 0, true>(h2b, w3a, km3a_in, km3a_out, h3, 20000, 27, N2c,
                                STRIDE_N2, 10, bins, ptr, bsums, rank, contrib,
                                cap, nullptr, nullptr, dst3a, stream);
    hipLaunchKernelGGL((make_scsh<128>), dim3(1), dim3(256), 0, stream,
                       dst3a, bn3a_g, bn3a_b, sc3a, sh3a, 1.0 / N2c);

    // ---- conv3b (128->256, K=27): cout-split into two 128-halves ----
    // One CSR for the layer; per half: phaseA (BN(h3)+ReLU fused) + single phaseB.
    {
        const int M = 20000, K = 27;
        Plan pl = make_plan((long long)K * M * 128, K, cap * 2, 10);
        build_csr2d(km3b_out, rank, bins, ptr, bsums, K * M, M, pl.q, pl.nch,
                    STRIDE_N2, stream);
        for (int half = 0; half < 2; ++half) {
            for (int ch = 0; ch < pl.nch; ++ch) {
                int k0 = ch * pl.q;
                int qc = std::min(pl.q, K - k0);
                dim3 g((20000 + 127) / 128, qc);
                hipLaunchKernelGGL((phaseA_mfma<128, 128, 256, 2>), g, dim3(256), 0, stream,
                                   h3, w3b + half * 128 + (size_t)k0 * 128 * 256,
                                   km3b_in + (size_t)k0 * M, km3b_out + (size_t)k0 * M,
                                   ptr + (size_t)ch * STRIDE_N2, rank + (size_t)k0 * M,
                                   contrib, M, sc3a, sh3a);
                bool last = (ch == pl.nch - 1);
                if (last)
                    hipLaunchKernelGGL((phaseB8<128, true>), dim3(2048), dim3(256), 0, stream,
                                       contrib, ptr + (size_t)ch * STRIDE_N2,
                                       x_e2 + half * 128, N2c, 256, ch ? 1 : 0,
                                       dst3b + half * 128, 256);
                else
                    hipLaunchKernelGGL((phaseB8<128, false>), dim3(2048), dim3(256), 0, stream,
                                       contrib, ptr + (size_t)ch * STRIDE_N2,
                                       x_e2 + half * 128, N2c, 256, ch ? 1 : 0,
                                       (double*)nullptr, 0);
            }
        }
        hipLaunchKernelGGL((bn_apply_relu_kernel<256>), dim3(2048), dim3(256), 0, stream,
                           x_e2, N2c, dst3b, bn3b_g, bn3b_b);
    }
}